// Round 4
// baseline (394.219 us; speedup 1.0000x reference)
//
#include <hip/hip_runtime.h>

#define B_ 4
#define L_ 1024
#define DIM_ 1024
#define H_ 8
#define D_ 32
#define LSEG 16
#define NSEG (L_/LSEG)   // 64

typedef __bf16 bf16_t;
typedef __bf16 bf16x8 __attribute__((ext_vector_type(8)));
typedef float f32x4 __attribute__((ext_vector_type(4)));

__device__ __forceinline__ void gload_lds16(const bf16_t* g, bf16_t* l) {
  __builtin_amdgcn_global_load_lds((const __attribute__((address_space(1))) void*)g,
                                   (__attribute__((address_space(3))) void*)l, 16, 0, 0);
}

// ---------------- merged f32 -> bf16 converts (5 regions, 1 launch) --------
// float4 units: x=1048576 (4096 blk), W_in=262144 (1024), W_qkva=524288 (2048),
// W_y=131072 (512), W_out=262144 (1024). Total 8704 blocks.
__global__ __launch_bounds__(256) void cvt_all(const float* __restrict__ x,
                                               const float* __restrict__ w1,
                                               const float* __restrict__ w2,
                                               const float* __restrict__ w3,
                                               const float* __restrict__ w4,
                                               bf16_t* __restrict__ ox,
                                               bf16_t* __restrict__ o1,
                                               bf16_t* __restrict__ o2,
                                               bf16_t* __restrict__ o3,
                                               bf16_t* __restrict__ o4) {
  int g = blockIdx.x;
  const float* in; bf16_t* out; int i;
  if      (g < 4096) { in = x;  out = ox; i = g * 256 + threadIdx.x; }
  else if (g < 5120) { in = w1; out = o1; i = (g - 4096) * 256 + threadIdx.x; }
  else if (g < 7168) { in = w2; out = o2; i = (g - 5120) * 256 + threadIdx.x; }
  else if (g < 7680) { in = w3; out = o3; i = (g - 7168) * 256 + threadIdx.x; }
  else               { in = w4; out = o4; i = (g - 7680) * 256 + threadIdx.x; }
  float4 v = ((const float4*)in)[i];
  union { bf16_t b[4]; unsigned long long q; } pk;
  pk.b[0] = (bf16_t)v.x; pk.b[1] = (bf16_t)v.y;
  pk.b[2] = (bf16_t)v.z; pk.b[3] = (bf16_t)v.w;
  ((unsigned long long*)out)[i] = pk.q;
}

// ---------------- NT GEMM, m97-style 128x128 -------------------------------
// C[m][n] = act(sum_k A[m][k]*B[n][k] + bias[n]); A:[M,K] bf16, B:[N,K] bf16.
// GATE=1: cols with (c&7)>=6 are (a_re,a_im) pairs -> apply unit-rot*sigmoid
// gate via shfl_xor(1) (re/im live in adjacent lanes of the C fragment).
template<int ACT, int OUTBF, int GATE>
__global__ __launch_bounds__(256) void gemm_nt(const bf16_t* __restrict__ A,
                                               const bf16_t* __restrict__ Bm,
                                               const float* __restrict__ bias,
                                               void* __restrict__ Cout,
                                               int M, int N, int K) {
  __shared__ __align__(16) bf16_t As[128 * 64];
  __shared__ __align__(16) bf16_t Bs[128 * 64];
  const int t = threadIdx.x;
  const int wid = t >> 6, lane = t & 63;
  const int wr = wid >> 1, wc = wid & 1;
  const int lr = lane & 15, lq = lane >> 4;
  const int bm = blockIdx.x, bn = blockIdx.y;
  const int rr = wid * 32 + (lane >> 3);
  const int c8 = (lane & 7) * 8;
  const bf16_t* Ag = A + (size_t)(bm * 128 + rr) * K + c8;
  const bf16_t* Bg = Bm + (size_t)(bn * 128 + rr) * K + c8;
  bf16_t* AsW = As + (wid * 32) * 64;
  bf16_t* BsW = Bs + (wid * 32) * 64;
  f32x4 acc[4][4] = {};
  for (int k0 = 0; k0 < K; k0 += 64) {
#pragma unroll
    for (int j = 0; j < 4; ++j)
      gload_lds16(Ag + (size_t)j * 8 * K, AsW + j * 8 * 64);
#pragma unroll
    for (int j = 0; j < 4; ++j)
      gload_lds16(Bg + (size_t)j * 8 * K, BsW + j * 8 * 64);
    Ag += 64; Bg += 64;
    __syncthreads();
#pragma unroll
    for (int ks = 0; ks < 2; ++ks) {
      bf16x8 af[4], bfv[4];
#pragma unroll
      for (int mi = 0; mi < 4; ++mi)
        af[mi] = *(const bf16x8*)&As[(wr * 64 + mi * 16 + lr) * 64 + ks * 32 + lq * 8];
#pragma unroll
      for (int ni = 0; ni < 4; ++ni)
        bfv[ni] = *(const bf16x8*)&Bs[(wc * 64 + ni * 16 + lr) * 64 + ks * 32 + lq * 8];
#pragma unroll
      for (int mi = 0; mi < 4; ++mi)
#pragma unroll
        for (int ni = 0; ni < 4; ++ni)
          acc[mi][ni] = __builtin_amdgcn_mfma_f32_16x16x32_bf16(af[mi], bfv[ni], acc[mi][ni], 0, 0, 0);
    }
    __syncthreads();
  }
#pragma unroll
  for (int mi = 0; mi < 4; ++mi) {
#pragma unroll
    for (int ni = 0; ni < 4; ++ni) {
      int colg = bn * 128 + wc * 64 + ni * 16 + lr;
      float bb = bias[colg];
#pragma unroll
      for (int r = 0; r < 4; ++r) {
        int rowg = bm * 128 + wr * 64 + mi * 16 + lq * 4 + r;
        float v = acc[mi][ni][r] + bb;
        if (ACT == 1) v = v / (1.0f + __expf(-v));
        if (GATE) {
          float wv = __shfl_xor(v, 1);
          if ((colg & 7) >= 6) {
            float m2 = v * v + wv * wv;
            v *= sqrtf(m2) / (1.0f + m2);
          }
        }
        if (OUTBF) ((bf16_t*)Cout)[(size_t)rowg * N + colg] = (bf16_t)v;
        else       ((float*)Cout)[(size_t)rowg * N + colg] = v;
      }
    }
  }
}

// ---------------- Pass 1: segmented scan, 1 wave/segment, 4dx4e tiles ------
// qkva per (b,l,h,d): [q_r,q_i,k_r,k_i,v_r,v_i,a_r,a_i] (a pre-gated).
// lane: dg=lane&7 -> d=dg*4+j; eg=lane>>3 -> e=eg*4+i. 16 complex states/lane.
__global__ __launch_bounds__(256) void scan_seg(const float* __restrict__ qkva,
                                                float* __restrict__ y_loc,
                                                float* __restrict__ qP,
                                                float* __restrict__ Aseg,
                                                float* __restrict__ Hfin) {
  const int t = threadIdx.x;
  const int wid = t >> 6, lane = t & 63;
  const int seg = blockIdx.x * 4 + wid;      // [0, 2048)
  const int s = seg & (NSEG - 1);
  const int bh = seg >> 6;                   // NSEG==64
  const int h = bh & (H_ - 1), b = bh >> 3;
  const int dg = lane & 7, eg = lane >> 3;
  const int d0 = dg * 4, e0 = eg * 4;
  float hr[4][4] = {}, hi[4][4] = {};
  float Pr[4] = {1,1,1,1}, Pi[4] = {0,0,0,0};
  const int STRIDE = H_ * D_ * 8;            // 2048 floats / step
  const float* bp = qkva + ((size_t)((b * L_ + s * LSEG) * H_ + h)) * (D_ * 8);
  size_t row = ((size_t)((b * L_ + s * LSEG) * H_ + h)) * D_;

  float4 qkA[4]; float2 aA[4], vA[4];
  float4 qkB[4]; float2 aB[4], vB[4];

#define LOADS(qk, aa, vv, ptr) { \
    _Pragma("unroll") for (int j = 0; j < 4; ++j) { \
      qk[j] = *(const float4*)((ptr) + (d0 + j) * 8); \
      aa[j] = *(const float2*)((ptr) + (d0 + j) * 8 + 6); } \
    _Pragma("unroll") for (int i = 0; i < 4; ++i) \
      vv[i] = *(const float2*)((ptr) + (e0 + i) * 8 + 4); }

#define STEP(qk, aa, vv) { \
    float ytr[4] = {0,0,0,0}, yti[4] = {0,0,0,0}; \
    float2 qpv[4]; \
    _Pragma("unroll") for (int j = 0; j < 4; ++j) { \
      float ar = aa[j].x, ai = aa[j].y; \
      float qr = qk[j].x, qi = qk[j].y, kr = qk[j].z, ki = qk[j].w; \
      float nPr = ar * Pr[j] - ai * Pi[j]; \
      float nPi = ar * Pi[j] + ai * Pr[j]; \
      Pr[j] = nPr; Pi[j] = nPi; \
      qpv[j].x = qr * nPr - qi * nPi; \
      qpv[j].y = qr * nPi + qi * nPr; \
      _Pragma("unroll") for (int i = 0; i < 4; ++i) { \
        float vr = vv[i].x, vi = vv[i].y; \
        float nhr = kr * vr - ki * vi + ar * hr[j][i] - ai * hi[j][i]; \
        float nhi = kr * vi + ki * vr + ar * hi[j][i] + ai * hr[j][i]; \
        hr[j][i] = nhr; hi[j][i] = nhi; \
        ytr[i] += qr * nhr - qi * nhi; \
        yti[i] += qr * nhi + qi * nhr; } } \
    _Pragma("unroll") for (int i = 0; i < 4; ++i) { \
      ytr[i] += __shfl_down(ytr[i], 4); yti[i] += __shfl_down(yti[i], 4); \
      ytr[i] += __shfl_down(ytr[i], 2); yti[i] += __shfl_down(yti[i], 2); \
      ytr[i] += __shfl_down(ytr[i], 1); yti[i] += __shfl_down(yti[i], 1); } \
    if (dg == 0) { \
      float4* yo = (float4*)(y_loc + (row + e0) * 2); \
      yo[0] = make_float4(ytr[0], yti[0], ytr[1], yti[1]); \
      yo[1] = make_float4(ytr[2], yti[2], ytr[3], yti[3]); } \
    if (eg == 0) { \
      float4* qo = (float4*)(qP + (row + d0) * 2); \
      qo[0] = make_float4(qpv[0].x, qpv[0].y, qpv[1].x, qpv[1].y); \
      qo[1] = make_float4(qpv[2].x, qpv[2].y, qpv[3].x, qpv[3].y); } \
    row += H_ * D_; }

  LOADS(qkA, aA, vA, bp);
#pragma unroll
  for (int l = 0; l < LSEG; l += 2) {
    LOADS(qkB, aB, vB, bp + STRIDE);
    STEP(qkA, aA, vA);
    if (l + 2 < LSEG) LOADS(qkA, aA, vA, bp + 2 * STRIDE);
    STEP(qkB, aB, vB);
    bp += 2 * STRIDE;
  }
#undef LOADS
#undef STEP
  const size_t segb = (size_t)seg * D_;
  if (eg == 0) {
    float4* ao = (float4*)(Aseg + (segb + d0) * 2);
    ao[0] = make_float4(Pr[0], Pi[0], Pr[1], Pi[1]);
    ao[1] = make_float4(Pr[2], Pi[2], Pr[3], Pi[3]);
  }
#pragma unroll
  for (int j = 0; j < 4; ++j) {
    float4* ho = (float4*)(Hfin + ((segb + d0 + j) * D_ + e0) * 2);
    ho[0] = make_float4(hr[j][0], hi[j][0], hr[j][1], hi[j][1]);
    ho[1] = make_float4(hr[j][2], hi[j][2], hr[j][3], hi[j][3]);
  }
}

// ---------------- Pass 2: combine segments (bh x e-quarter WGs) ------------
__global__ __launch_bounds__(256) void seg_combine(const float* __restrict__ h0re,
                                                   const float* __restrict__ h0im,
                                                   const float* __restrict__ Aseg,
                                                   const float* __restrict__ Hfin,
                                                   float* __restrict__ Hc) {
  const int bh = blockIdx.x >> 2;
  const int eq = blockIdx.x & 3;
  const int h = bh & (H_ - 1);
  const int t = threadIdx.x;
  const int d = t >> 3;
  const int e = eq * 8 + (t & 7);
  float cr = h0re[((size_t)h * D_ + d) * D_ + e];
  float ci = h0im[((size_t)h * D_ + d) * D_ + e];
  size_t idx = ((size_t)bh * NSEG * D_ + d) * D_ + e;   // advances by D_*D_
  size_t aidx = (size_t)bh * NSEG * D_ + d;             // advances by D_
  float2 A0 = *(const float2*)(Aseg + aidx * 2);
  float2 F0 = *(const float2*)(Hfin + idx * 2);
  for (int s = 0; s < NSEG; ++s) {
    float2 A1, F1;
    if (s + 1 < NSEG) {
      A1 = *(const float2*)(Aseg + (aidx + D_) * 2);
      F1 = *(const float2*)(Hfin + (idx + D_ * D_) * 2);
    }
    *(float2*)(Hc + idx * 2) = make_float2(cr, ci);
    float nr = A0.x * cr - A0.y * ci + F0.x;
    float ni = A0.x * ci + A0.y * cr + F0.y;
    cr = nr; ci = ni;
    A0 = A1; F0 = F1;
    idx += D_ * D_; aidx += D_;
  }
}

// ---------------- Pass 3: y += qP @ Hcarry; emit y2 (bf16) ----------------
__global__ __launch_bounds__(256) void y_correct(const float* __restrict__ y_loc,
                                                 const float* __restrict__ qP,
                                                 const float* __restrict__ Hc,
                                                 bf16_t* __restrict__ y2b) {
  __shared__ __align__(16) float Hs[D_ * D_ * 2];   // 8 KB
  const int seg = blockIdx.x;
  const int s = seg & (NSEG - 1);
  const int bh = seg >> 6;
  const int h = bh & (H_ - 1), b = bh >> 3;
  const int t = threadIdx.x;
  const float4* src = (const float4*)(Hc + (size_t)seg * (D_ * D_ * 2));
  ((float4*)Hs)[t] = src[t];
  ((float4*)Hs)[t + 256] = src[t + 256];
  __syncthreads();
  const int l = t >> 4;            // 0..15
  const int ep = (t & 15) * 2;     // 2 e per thread
  const int lg = s * LSEG + l;
  const size_t rowc = ((size_t)(b * L_ + lg) * H_ + h) * D_;
  const float* qpr = qP + rowc * 2;
  float4 y0 = *(const float4*)(y_loc + (rowc + ep) * 2);
  float ac_r[2] = {y0.x, y0.z}, ac_i[2] = {y0.y, y0.w};
#pragma unroll 4
  for (int d = 0; d < D_; ++d) {
    float2 p = *(const float2*)(qpr + d * 2);
    float4 hv = *(const float4*)&Hs[(d * D_ + ep) * 2];
    ac_r[0] += p.x * hv.x - p.y * hv.y; ac_i[0] += p.x * hv.y + p.y * hv.x;
    ac_r[1] += p.x * hv.z - p.y * hv.w; ac_i[1] += p.x * hv.w + p.y * hv.z;
  }
  union { bf16_t bv[4]; uint2 q; } pk;
  pk.bv[0] = (bf16_t)ac_r[0]; pk.bv[1] = (bf16_t)ac_i[0];
  pk.bv[2] = (bf16_t)ac_r[1]; pk.bv[3] = (bf16_t)ac_i[1];
  *(uint2*)(y2b + (size_t)(b * L_ + lg) * (H_ * D_ * 2) + (h * D_ + ep) * 2) = pk.q;
}

// ---------------- launcher ------------------------------------------------
extern "C" void kernel_launch(void* const* d_in, const int* in_sizes, int n_in,
                              void* d_out, int out_size, void* d_ws, size_t ws_size,
                              hipStream_t stream) {
  const float* x      = (const float*)d_in[0];
  const float* W_in   = (const float*)d_in[1];
  const float* b_in   = (const float*)d_in[2];
  const float* W_qkva = (const float*)d_in[3];
  const float* b_qkva = (const float*)d_in[4];
  const float* W_y    = (const float*)d_in[5];
  const float* b_y    = (const float*)d_in[6];
  const float* W_out  = (const float*)d_in[7];
  const float* b_out  = (const float*)d_in[8];
  const float* h0re   = (const float*)d_in[9];
  const float* h0im   = (const float*)d_in[10];

  char* w = (char*)d_ws;
  const size_t MB = 1ull << 20;
  bf16_t* Wb_in   = (bf16_t*)(w + 0*MB);    // 2 MB
  bf16_t* Wb_qkva = (bf16_t*)(w + 2*MB);    // 4 MB
  bf16_t* Wb_y    = (bf16_t*)(w + 6*MB);    // 1 MB
  bf16_t* Wb_out  = (bf16_t*)(w + 7*MB);    // 2 MB
  bf16_t* xb      = (bf16_t*)(w + 9*MB);    // 8 MB (dead after GEMM1)
  float*  qP      = (float*) (w + 9*MB);    // 8 MB (overlay xb)
  bf16_t* u       = (bf16_t*)(w + 17*MB);   // 8 MB (dead after GEMM2)
  float*  y_loc   = (float*) (w + 17*MB);   // 8 MB (overlay u)
  float*  qkva    = (float*) (w + 25*MB);   // 32 MB (dead after scan)
  float*  Hc      = (float*) (w + 25*MB);   // 16 MB (overlay qkva)
  bf16_t* y2b     = (bf16_t*)(w + 41*MB);   // 4 MB (overlay qkva)
  bf16_t* z       = (bf16_t*)(w + 45*MB);   // 8 MB (overlay qkva)
  float*  Aseg    = (float*) (w + 57*MB);   // 0.5 MB
  float*  Hfin    = (float*) (w + 58*MB);   // 16 MB -> total 74 MB

  cvt_all<<<8704, 256, 0, stream>>>(x, W_in, W_qkva, W_y, W_out,
                                    xb, Wb_in, Wb_qkva, Wb_y, Wb_out);

  // u = silu(x @ W_in^T + b_in)
  gemm_nt<1,1,0><<<dim3(32, 8), 256, 0, stream>>>(xb, Wb_in, b_in, u, 4096, 1024, 1024);
  // qkva = u @ W_qkva^T + b_qkva (f32), a-cols gated in epilogue
  gemm_nt<0,0,1><<<dim3(32, 16), 256, 0, stream>>>(u, Wb_qkva, b_qkva, qkva, 4096, 2048, 1024);
  // recurrence
  scan_seg   <<<512, 256, 0, stream>>>(qkva, y_loc, qP, Aseg, Hfin);
  seg_combine<<<128, 256, 0, stream>>>(h0re, h0im, Aseg, Hfin, Hc);
  y_correct  <<<2048, 256, 0, stream>>>(y_loc, qP, Hc, y2b);
  // z = silu(y2 @ W_y^T + b_y)
  gemm_nt<1,1,0><<<dim3(32, 8), 256, 0, stream>>>(y2b, Wb_y, b_y, z, 4096, 1024, 512);
  // out = z @ W_out^T + b_out (f32)
  gemm_nt<0,0,0><<<dim3(32, 8), 256, 0, stream>>>(z, Wb_out, b_out, (float*)d_out, 4096, 1024, 1024);
}

// Round 5
// 244.333 us; speedup vs baseline: 1.6135x; 1.6135x over previous
//
#include <hip/hip_runtime.h>

#define B_ 4
#define L_ 1024
#define DIM_ 1024
#define H_ 8
#define D_ 32
#define LSEG 16
#define NSEG (L_/LSEG)   // 64

typedef __bf16 bf16_t;
typedef __bf16 bf16x8 __attribute__((ext_vector_type(8)));
typedef float f32x4 __attribute__((ext_vector_type(4)));

__device__ __forceinline__ void gload_lds16(const bf16_t* g, bf16_t* l) {
  __builtin_amdgcn_global_load_lds((const __attribute__((address_space(1))) void*)g,
                                   (__attribute__((address_space(3))) void*)l, 16, 0, 0);
}
__device__ __forceinline__ void gload_lds16f(const float* g, float* l) {
  __builtin_amdgcn_global_load_lds((const __attribute__((address_space(1))) void*)g,
                                   (__attribute__((address_space(3))) void*)l, 16, 0, 0);
}

// ---------------- merged f32 -> bf16 converts (5 regions, 1 launch) --------
// float4 units: x=1048576 (4096 blk), W_in=262144 (1024), W_qkva=524288 (2048),
// W_y=131072 (512), W_out=262144 (1024). Total 8704 blocks.
__global__ __launch_bounds__(256) void cvt_all(const float* __restrict__ x,
                                               const float* __restrict__ w1,
                                               const float* __restrict__ w2,
                                               const float* __restrict__ w3,
                                               const float* __restrict__ w4,
                                               bf16_t* __restrict__ ox,
                                               bf16_t* __restrict__ o1,
                                               bf16_t* __restrict__ o2,
                                               bf16_t* __restrict__ o3,
                                               bf16_t* __restrict__ o4) {
  int g = blockIdx.x;
  const float* in; bf16_t* out; int i;
  if      (g < 4096) { in = x;  out = ox; i = g * 256 + threadIdx.x; }
  else if (g < 5120) { in = w1; out = o1; i = (g - 4096) * 256 + threadIdx.x; }
  else if (g < 7168) { in = w2; out = o2; i = (g - 5120) * 256 + threadIdx.x; }
  else if (g < 7680) { in = w3; out = o3; i = (g - 7168) * 256 + threadIdx.x; }
  else               { in = w4; out = o4; i = (g - 7680) * 256 + threadIdx.x; }
  float4 v = ((const float4*)in)[i];
  union { bf16_t b[4]; unsigned long long q; } pk;
  pk.b[0] = (bf16_t)v.x; pk.b[1] = (bf16_t)v.y;
  pk.b[2] = (bf16_t)v.z; pk.b[3] = (bf16_t)v.w;
  ((unsigned long long*)out)[i] = pk.q;
}

// ---------------- NT GEMM, m97-style, BM=128, BN in {64,128} ---------------
// C[m][n] = act(sum_k A[m][k]*B[n][k] + bias[n]); A:[M,K] bf16, B:[N,K] bf16.
// GATE=1: cols with (c&7)>=6 are (a_re,a_im) pairs -> unit-rot*sigmoid gate
// via shfl_xor(1). TRANS=1: scatter-store C to [b,h,l,256] f32 layout.
template<int BN, int ACT, int OUTBF, int GATE, int TRANS>
__global__ __launch_bounds__(256) void gemm_nt(const bf16_t* __restrict__ A,
                                               const bf16_t* __restrict__ Bm,
                                               const float* __restrict__ bias,
                                               void* __restrict__ Cout,
                                               int M, int N, int K) {
  constexpr int NI = BN / 32;          // mfma col-tiles per wave
  constexpr int ISS_B = BN / 32;       // B staging issues per wave
  __shared__ __align__(16) bf16_t As[128 * 64];
  __shared__ __align__(16) bf16_t Bs[BN * 64];
  const int t = threadIdx.x;
  const int wid = t >> 6, lane = t & 63;
  const int wr = wid >> 1, wc = wid & 1;
  const int lr = lane & 15, lq = lane >> 4;
  const int bm = blockIdx.x, bn = blockIdx.y;
  const int rA = wid * 32 + (lane >> 3);
  const int rB = wid * (BN / 4) + (lane >> 3);
  const int c8 = (lane & 7) * 8;
  const bf16_t* Ag = A + (size_t)(bm * 128 + rA) * K + c8;
  const bf16_t* Bg = Bm + (size_t)(bn * BN + rB) * K + c8;
  bf16_t* AsW = As + (wid * 32) * 64;
  bf16_t* BsW = Bs + (wid * (BN / 4)) * 64;
  f32x4 acc[4][NI] = {};
  for (int k0 = 0; k0 < K; k0 += 64) {
#pragma unroll
    for (int j = 0; j < 4; ++j)
      gload_lds16(Ag + (size_t)j * 8 * K, AsW + j * 8 * 64);
#pragma unroll
    for (int j = 0; j < ISS_B; ++j)
      gload_lds16(Bg + (size_t)j * 8 * K, BsW + j * 8 * 64);
    Ag += 64; Bg += 64;
    __syncthreads();
#pragma unroll
    for (int ks = 0; ks < 2; ++ks) {
      bf16x8 af[4], bfv[NI];
#pragma unroll
      for (int mi = 0; mi < 4; ++mi)
        af[mi] = *(const bf16x8*)&As[(wr * 64 + mi * 16 + lr) * 64 + ks * 32 + lq * 8];
#pragma unroll
      for (int ni = 0; ni < NI; ++ni)
        bfv[ni] = *(const bf16x8*)&Bs[(wc * (BN/2) + ni * 16 + lr) * 64 + ks * 32 + lq * 8];
#pragma unroll
      for (int mi = 0; mi < 4; ++mi)
#pragma unroll
        for (int ni = 0; ni < NI; ++ni)
          acc[mi][ni] = __builtin_amdgcn_mfma_f32_16x16x32_bf16(af[mi], bfv[ni], acc[mi][ni], 0, 0, 0);
    }
    __syncthreads();
  }
#pragma unroll
  for (int mi = 0; mi < 4; ++mi) {
#pragma unroll
    for (int ni = 0; ni < NI; ++ni) {
      int colg = bn * BN + wc * (BN/2) + ni * 16 + lr;
      float bb = bias[colg];
#pragma unroll
      for (int r = 0; r < 4; ++r) {
        int rowg = bm * 128 + wr * 64 + mi * 16 + lq * 4 + r;
        float v = acc[mi][ni][r] + bb;
        if (ACT == 1) v = v / (1.0f + __expf(-v));
        if (GATE) {
          float wv = __shfl_xor(v, 1);
          if ((colg & 7) >= 6) {
            float m2 = v * v + wv * wv;
            v *= sqrtf(m2) / (1.0f + m2);
          }
        }
        if (TRANS) {
          // [b,h,l,dc]: b=rowg>>10, l=rowg&1023, h=colg>>8, dc=colg&255
          size_t idx = (((size_t)((rowg >> 10) * 8 + (colg >> 8))) * 1024
                        + (rowg & 1023)) * 256 + (colg & 255);
          ((float*)Cout)[idx] = v;
        } else if (OUTBF) {
          ((bf16_t*)Cout)[(size_t)rowg * N + colg] = (bf16_t)v;
        } else {
          ((float*)Cout)[(size_t)rowg * N + colg] = v;
        }
      }
    }
  }
}

// ---------------- Pass 1: scan, 1 block/segment, LDS-staged ----------------
// qkvaT layout [b,h,l,d,c]: segment = contiguous 16KB. Stage whole segment
// via global_load_lds (4 dense 4KB issues), then 16 serial steps from LDS.
// lane: dg=lane&7 -> d in {dg, dg+8, dg+16, dg+24} (2-way LDS conflicts only);
// e = wid*8 + (lane>>3). 4 complex states/lane.
__global__ __launch_bounds__(256) void scan_seg(const float* __restrict__ qkvaT,
                                                float* __restrict__ y_loc,
                                                float* __restrict__ qP,
                                                float* __restrict__ Aseg,
                                                float* __restrict__ Hfin) {
  __shared__ __align__(16) float Q[LSEG * 256];    // 16 KB
  const int t = threadIdx.x;
  const int seg = blockIdx.x;              // [0, 2048)
  const int s = seg & (NSEG - 1);
  const int bh = seg >> 6;                 // NSEG==64
  const int h = bh & (H_ - 1), b = bh >> 3;
  const int wid = t >> 6, lane = t & 63;
  const int dg = lane & 7, eh = lane >> 3;
  const int e = wid * 8 + eh;
  const float* gb = qkvaT + ((size_t)bh * L_ + s * LSEG) * 256;
#pragma unroll
  for (int c = 0; c < 4; ++c)
    gload_lds16f(gb + c * 1024 + t * 4, Q + c * 1024 + wid * 256);
  __syncthreads();
  float hr[4] = {}, hi[4] = {};
  float Pr[4] = {1,1,1,1}, Pi[4] = {0,0,0,0};
  size_t row = ((size_t)(b * L_ + s * LSEG) * H_ + h) * D_;
  for (int l = 0; l < LSEG; ++l) {
    const float* R = Q + l * 256;
    float2 vv = *(const float2*)(R + e * 8 + 4);
    float ytr = 0.f, yti = 0.f;
    float2 qpv[4];
#pragma unroll
    for (int j = 0; j < 4; ++j) {
      const int d = dg + 8 * j;
      float4 qk = *(const float4*)(R + d * 8);
      float2 aa = *(const float2*)(R + d * 8 + 6);
      float nPr = aa.x * Pr[j] - aa.y * Pi[j];
      float nPi = aa.x * Pi[j] + aa.y * Pr[j];
      Pr[j] = nPr; Pi[j] = nPi;
      qpv[j].x = qk.x * nPr - qk.y * nPi;
      qpv[j].y = qk.x * nPi + qk.y * nPr;
      float kvr = qk.z * vv.x - qk.w * vv.y;
      float kvi = qk.z * vv.y + qk.w * vv.x;
      float nhr = aa.x * hr[j] - aa.y * hi[j] + kvr;
      float nhi = aa.x * hi[j] + aa.y * hr[j] + kvi;
      hr[j] = nhr; hi[j] = nhi;
      ytr += qk.x * nhr - qk.y * nhi;
      yti += qk.x * nhi + qk.y * nhr;
    }
    ytr += __shfl_down(ytr, 4); yti += __shfl_down(yti, 4);
    ytr += __shfl_down(ytr, 2); yti += __shfl_down(yti, 2);
    ytr += __shfl_down(ytr, 1); yti += __shfl_down(yti, 1);
    if (dg == 0)
      *(float2*)(y_loc + (row + e) * 2) = make_float2(ytr, yti);
    if (t < 8) {   // wave 0, eh==0: lanes 0..7 hold all d's qp
#pragma unroll
      for (int j = 0; j < 4; ++j)
        *(float2*)(qP + (row + dg + 8 * j) * 2) = qpv[j];
    }
    row += H_ * D_;
  }
  const size_t segb = (size_t)seg * D_;
  if (t < 8) {
#pragma unroll
    for (int j = 0; j < 4; ++j)
      *(float2*)(Aseg + (segb + dg + 8 * j) * 2) = make_float2(Pr[j], Pi[j]);
  }
#pragma unroll
  for (int j = 0; j < 4; ++j)
    *(float2*)(Hfin + ((segb + dg + 8 * j) * D_ + e) * 2) = make_float2(hr[j], hi[j]);
}

// ---------------- Pass 2: combine segments (bh x e-quarter WGs) ------------
__global__ __launch_bounds__(256) void seg_combine(const float* __restrict__ h0re,
                                                   const float* __restrict__ h0im,
                                                   const float* __restrict__ Aseg,
                                                   const float* __restrict__ Hfin,
                                                   float* __restrict__ Hc) {
  const int bh = blockIdx.x >> 2;
  const int eq = blockIdx.x & 3;
  const int h = bh & (H_ - 1);
  const int t = threadIdx.x;
  const int d = t >> 3;
  const int e = eq * 8 + (t & 7);
  float cr = h0re[((size_t)h * D_ + d) * D_ + e];
  float ci = h0im[((size_t)h * D_ + d) * D_ + e];
  size_t idx = ((size_t)bh * NSEG * D_ + d) * D_ + e;   // advances by D_*D_
  size_t aidx = (size_t)bh * NSEG * D_ + d;             // advances by D_
  float2 A0 = *(const float2*)(Aseg + aidx * 2);
  float2 F0 = *(const float2*)(Hfin + idx * 2);
  for (int s = 0; s < NSEG; ++s) {
    float2 A1, F1;
    if (s + 1 < NSEG) {
      A1 = *(const float2*)(Aseg + (aidx + D_) * 2);
      F1 = *(const float2*)(Hfin + (idx + D_ * D_) * 2);
    }
    *(float2*)(Hc + idx * 2) = make_float2(cr, ci);
    float nr = A0.x * cr - A0.y * ci + F0.x;
    float ni = A0.x * ci + A0.y * cr + F0.y;
    cr = nr; ci = ni;
    A0 = A1; F0 = F1;
    idx += D_ * D_; aidx += D_;
  }
}

// ---------------- Pass 3: y += qP @ Hcarry; emit y2 (bf16) ----------------
__global__ __launch_bounds__(256) void y_correct(const float* __restrict__ y_loc,
                                                 const float* __restrict__ qP,
                                                 const float* __restrict__ Hc,
                                                 bf16_t* __restrict__ y2b) {
  __shared__ __align__(16) float Hs[D_ * D_ * 2];   // 8 KB
  const int seg = blockIdx.x;
  const int s = seg & (NSEG - 1);
  const int bh = seg >> 6;
  const int h = bh & (H_ - 1), b = bh >> 3;
  const int t = threadIdx.x;
  const float4* src = (const float4*)(Hc + (size_t)seg * (D_ * D_ * 2));
  ((float4*)Hs)[t] = src[t];
  ((float4*)Hs)[t + 256] = src[t + 256];
  __syncthreads();
  const int l = t >> 4;            // 0..15
  const int ep = (t & 15) * 2;     // 2 e per thread
  const int lg = s * LSEG + l;
  const size_t rowc = ((size_t)(b * L_ + lg) * H_ + h) * D_;
  const float* qpr = qP + rowc * 2;
  float4 y0 = *(const float4*)(y_loc + (rowc + ep) * 2);
  float ac_r[2] = {y0.x, y0.z}, ac_i[2] = {y0.y, y0.w};
#pragma unroll 4
  for (int d = 0; d < D_; ++d) {
    float2 p = *(const float2*)(qpr + d * 2);
    float4 hv = *(const float4*)&Hs[(d * D_ + ep) * 2];
    ac_r[0] += p.x * hv.x - p.y * hv.y; ac_i[0] += p.x * hv.y + p.y * hv.x;
    ac_r[1] += p.x * hv.z - p.y * hv.w; ac_i[1] += p.x * hv.w + p.y * hv.z;
  }
  union { bf16_t bv[4]; uint2 q; } pk;
  pk.bv[0] = (bf16_t)ac_r[0]; pk.bv[1] = (bf16_t)ac_i[0];
  pk.bv[2] = (bf16_t)ac_r[1]; pk.bv[3] = (bf16_t)ac_i[1];
  *(uint2*)(y2b + (size_t)(b * L_ + lg) * (H_ * D_ * 2) + (h * D_ + ep) * 2) = pk.q;
}

// ---------------- launcher ------------------------------------------------
extern "C" void kernel_launch(void* const* d_in, const int* in_sizes, int n_in,
                              void* d_out, int out_size, void* d_ws, size_t ws_size,
                              hipStream_t stream) {
  const float* x      = (const float*)d_in[0];
  const float* W_in   = (const float*)d_in[1];
  const float* b_in   = (const float*)d_in[2];
  const float* W_qkva = (const float*)d_in[3];
  const float* b_qkva = (const float*)d_in[4];
  const float* W_y    = (const float*)d_in[5];
  const float* b_y    = (const float*)d_in[6];
  const float* W_out  = (const float*)d_in[7];
  const float* b_out  = (const float*)d_in[8];
  const float* h0re   = (const float*)d_in[9];
  const float* h0im   = (const float*)d_in[10];

  char* w = (char*)d_ws;
  const size_t MB = 1ull << 20;
  bf16_t* Wb_in   = (bf16_t*)(w + 0*MB);    // 2 MB
  bf16_t* Wb_qkva = (bf16_t*)(w + 2*MB);    // 4 MB
  bf16_t* Wb_y    = (bf16_t*)(w + 6*MB);    // 1 MB
  bf16_t* Wb_out  = (bf16_t*)(w + 7*MB);    // 2 MB
  bf16_t* xb      = (bf16_t*)(w + 9*MB);    // 8 MB (dead after GEMM1)
  float*  qP      = (float*) (w + 9*MB);    // 8 MB (overlay xb)
  bf16_t* u       = (bf16_t*)(w + 17*MB);   // 8 MB (dead after GEMM2)
  float*  y_loc   = (float*) (w + 17*MB);   // 8 MB (overlay u)
  float*  qkvaT   = (float*) (w + 25*MB);   // 32 MB [b,h,l,256] (dead after scan)
  float*  Hc      = (float*) (w + 25*MB);   // 16 MB (overlay qkvaT)
  bf16_t* y2b     = (bf16_t*)(w + 41*MB);   // 4 MB (overlay qkvaT)
  bf16_t* z       = (bf16_t*)(w + 45*MB);   // 8 MB (overlay qkvaT)
  float*  Aseg    = (float*) (w + 57*MB);   // 0.5 MB
  float*  Hfin    = (float*) (w + 58*MB);   // 16 MB -> total 74 MB

  cvt_all<<<8704, 256, 0, stream>>>(x, W_in, W_qkva, W_y, W_out,
                                    xb, Wb_in, Wb_qkva, Wb_y, Wb_out);

  // u = silu(x @ W_in^T + b_in)                          512 blocks
  gemm_nt<64,1,1,0,0><<<dim3(32, 16), 256, 0, stream>>>(xb, Wb_in, b_in, u, 4096, 1024, 1024);
  // qkvaT = gate(u @ W_qkva^T + b_qkva), transposed store  512 blocks
  gemm_nt<128,0,0,1,1><<<dim3(32, 16), 256, 0, stream>>>(u, Wb_qkva, b_qkva, qkvaT, 4096, 2048, 1024);
  // recurrence
  scan_seg   <<<2048, 256, 0, stream>>>(qkvaT, y_loc, qP, Aseg, Hfin);
  seg_combine<<<128,  256, 0, stream>>>(h0re, h0im, Aseg, Hfin, Hc);
  y_correct  <<<2048, 256, 0, stream>>>(y_loc, qP, Hc, y2b);
  // z = silu(y2 @ W_y^T + b_y)                           512 blocks
  gemm_nt<64,1,1,0,0><<<dim3(32, 16), 256, 0, stream>>>(y2b, Wb_y, b_y, z, 4096, 1024, 512);
  // out = z @ W_out^T + b_out                            512 blocks
  gemm_nt<64,0,0,0,0><<<dim3(32, 16), 256, 0, stream>>>(z, Wb_out, b_out, (float*)d_out, 4096, 1024, 1024);
}

// Round 6
// 234.892 us; speedup vs baseline: 1.6783x; 1.0402x over previous
//
#include <hip/hip_runtime.h>

#define B_ 4
#define L_ 1024
#define DIM_ 1024
#define H_ 8
#define D_ 32
#define LSEG 16
#define NSEG (L_/LSEG)   // 64

typedef __bf16 bf16_t;
typedef __bf16 bf16x8 __attribute__((ext_vector_type(8)));
typedef float f32x4 __attribute__((ext_vector_type(4)));

__device__ __forceinline__ void gload_lds16(const bf16_t* g, bf16_t* l) {
  __builtin_amdgcn_global_load_lds((const __attribute__((address_space(1))) void*)g,
                                   (__attribute__((address_space(3))) void*)l, 16, 0, 0);
}
__device__ __forceinline__ void gload_lds16f(const float* g, float* l) {
  __builtin_amdgcn_global_load_lds((const __attribute__((address_space(1))) void*)g,
                                   (__attribute__((address_space(3))) void*)l, 16, 0, 0);
}

// ---------------- merged f32 -> bf16 converts (5 regions, 1 launch) --------
// float4 units: x=1048576 (4096 blk), W_in=262144 (1024), W_qkva=524288 (2048),
// W_y=131072 (512), W_out=262144 (1024). Total 8704 blocks.
__global__ __launch_bounds__(256) void cvt_all(const float* __restrict__ x,
                                               const float* __restrict__ w1,
                                               const float* __restrict__ w2,
                                               const float* __restrict__ w3,
                                               const float* __restrict__ w4,
                                               bf16_t* __restrict__ ox,
                                               bf16_t* __restrict__ o1,
                                               bf16_t* __restrict__ o2,
                                               bf16_t* __restrict__ o3,
                                               bf16_t* __restrict__ o4) {
  int g = blockIdx.x;
  const float* in; bf16_t* out; int i;
  if      (g < 4096) { in = x;  out = ox; i = g * 256 + threadIdx.x; }
  else if (g < 5120) { in = w1; out = o1; i = (g - 4096) * 256 + threadIdx.x; }
  else if (g < 7168) { in = w2; out = o2; i = (g - 5120) * 256 + threadIdx.x; }
  else if (g < 7680) { in = w3; out = o3; i = (g - 7168) * 256 + threadIdx.x; }
  else               { in = w4; out = o4; i = (g - 7680) * 256 + threadIdx.x; }
  float4 v = ((const float4*)in)[i];
  union { bf16_t b[4]; unsigned long long q; } pk;
  pk.b[0] = (bf16_t)v.x; pk.b[1] = (bf16_t)v.y;
  pk.b[2] = (bf16_t)v.z; pk.b[3] = (bf16_t)v.w;
  ((unsigned long long*)out)[i] = pk.q;
}

// ---------------- NT GEMM, m97-style + XOR bank swizzle --------------------
// C[m][n] = act(sum_k A[m][k]*B[n][k] + bias[n]); A:[M,K] bf16, B:[N,K] bf16.
// LDS tiles are [row][64] bf16 (128 B row stride == 32 banks), so 16B slot s
// of row r holds GLOBAL slot s^(r&7); fragment reads use slot sg^(r&7).
// This spreads the 16 lr-lanes of each ds_read_b128 over all 32 banks
// (only the free 2-way lr/lr+8 alias remains). Staging keeps the exact
// wave-uniform-base+lane*16 dest global_load_lds requires.
// GATE=1: cols with (c&7)>=6 are (a_re,a_im) pairs -> unit-rot*sigmoid gate
// via shfl_xor(1). TRANS=1: scatter-store C to [b,h,l,256] f32 layout.
template<int BN, int ACT, int OUTBF, int GATE, int TRANS>
__global__ __launch_bounds__(256) void gemm_nt(const bf16_t* __restrict__ A,
                                               const bf16_t* __restrict__ Bm,
                                               const float* __restrict__ bias,
                                               void* __restrict__ Cout,
                                               int M, int N, int K) {
  constexpr int NI = BN / 32;          // mfma col-tiles per wave
  constexpr int ISS_B = BN / 32;       // B staging issues per wave
  __shared__ __align__(16) bf16_t As[128 * 64];
  __shared__ __align__(16) bf16_t Bs[BN * 64];
  const int t = threadIdx.x;
  const int wid = t >> 6, lane = t & 63;
  const int wr = wid >> 1, wc = wid & 1;
  const int lr = lane & 15, lq = lane >> 4;
  const int bm = blockIdx.x, bn = blockIdx.y;
  const int rA = wid * 32 + (lane >> 3);
  const int rB = wid * (BN / 4) + (lane >> 3);
  // staging col: this lane fills LDS slot (lane&7) of its row; fetch the
  // swizzled global slot (lane&7)^(row&7). row&7 == (lane>>3)&7 for both A,B.
  const int c8 = (((lane & 7) ^ ((lane >> 3) & 7))) * 8;
  const bf16_t* Ag = A + (size_t)(bm * 128 + rA) * K + c8;
  const bf16_t* Bg = Bm + (size_t)(bn * BN + rB) * K + c8;
  bf16_t* AsW = As + (wid * 32) * 64;
  bf16_t* BsW = Bs + (wid * (BN / 4)) * 64;
  f32x4 acc[4][NI] = {};
  for (int k0 = 0; k0 < K; k0 += 64) {
#pragma unroll
    for (int j = 0; j < 4; ++j)
      gload_lds16(Ag + (size_t)j * 8 * K, AsW + j * 8 * 64);
#pragma unroll
    for (int j = 0; j < ISS_B; ++j)
      gload_lds16(Bg + (size_t)j * 8 * K, BsW + j * 8 * 64);
    Ag += 64; Bg += 64;
    __syncthreads();
#pragma unroll
    for (int ks = 0; ks < 2; ++ks) {
      const int sg = ks * 4 + lq;            // global 16B slot wanted
      const int sl = (sg ^ (lr & 7)) * 8;    // swizzled LDS col (elements)
      bf16x8 af[4], bfv[NI];
#pragma unroll
      for (int mi = 0; mi < 4; ++mi)
        af[mi] = *(const bf16x8*)&As[(wr * 64 + mi * 16 + lr) * 64 + sl];
#pragma unroll
      for (int ni = 0; ni < NI; ++ni)
        bfv[ni] = *(const bf16x8*)&Bs[(wc * (BN/2) + ni * 16 + lr) * 64 + sl];
#pragma unroll
      for (int mi = 0; mi < 4; ++mi)
#pragma unroll
        for (int ni = 0; ni < NI; ++ni)
          acc[mi][ni] = __builtin_amdgcn_mfma_f32_16x16x32_bf16(af[mi], bfv[ni], acc[mi][ni], 0, 0, 0);
    }
    __syncthreads();
  }
#pragma unroll
  for (int mi = 0; mi < 4; ++mi) {
#pragma unroll
    for (int ni = 0; ni < NI; ++ni) {
      int colg = bn * BN + wc * (BN/2) + ni * 16 + lr;
      float bb = bias[colg];
#pragma unroll
      for (int r = 0; r < 4; ++r) {
        int rowg = bm * 128 + wr * 64 + mi * 16 + lq * 4 + r;
        float v = acc[mi][ni][r] + bb;
        if (ACT == 1) v = v / (1.0f + __expf(-v));
        if (GATE) {
          float wv = __shfl_xor(v, 1);
          if ((colg & 7) >= 6) {
            float m2 = v * v + wv * wv;
            v *= sqrtf(m2) / (1.0f + m2);
          }
        }
        if (TRANS) {
          // [b,h,l,dc]: b=rowg>>10, l=rowg&1023, h=colg>>8, dc=colg&255
          size_t idx = (((size_t)((rowg >> 10) * 8 + (colg >> 8))) * 1024
                        + (rowg & 1023)) * 256 + (colg & 255);
          ((float*)Cout)[idx] = v;
        } else if (OUTBF) {
          ((bf16_t*)Cout)[(size_t)rowg * N + colg] = (bf16_t)v;
        } else {
          ((float*)Cout)[(size_t)rowg * N + colg] = v;
        }
      }
    }
  }
}

// ---------------- Pass 1: scan, 1 block/segment, LDS-staged ----------------
// qkvaT layout [b,h,l,d,c]: segment = contiguous 16KB. Stage whole segment
// via global_load_lds (4 dense 4KB issues), then 16 serial steps from LDS.
// lane: dg=lane&7 -> d in {dg, dg+8, dg+16, dg+24} (2-way LDS conflicts only);
// e = wid*8 + (lane>>3). 4 complex states/lane.
__global__ __launch_bounds__(256) void scan_seg(const float* __restrict__ qkvaT,
                                                float* __restrict__ y_loc,
                                                float* __restrict__ qP,
                                                float* __restrict__ Aseg,
                                                float* __restrict__ Hfin) {
  __shared__ __align__(16) float Q[LSEG * 256];    // 16 KB
  const int t = threadIdx.x;
  const int seg = blockIdx.x;              // [0, 2048)
  const int s = seg & (NSEG - 1);
  const int bh = seg >> 6;                 // NSEG==64
  const int h = bh & (H_ - 1), b = bh >> 3;
  const int wid = t >> 6, lane = t & 63;
  const int dg = lane & 7, eh = lane >> 3;
  const int e = wid * 8 + eh;
  const float* gb = qkvaT + ((size_t)bh * L_ + s * LSEG) * 256;
#pragma unroll
  for (int c = 0; c < 4; ++c)
    gload_lds16f(gb + c * 1024 + t * 4, Q + c * 1024 + wid * 256);
  __syncthreads();
  float hr[4] = {}, hi[4] = {};
  float Pr[4] = {1,1,1,1}, Pi[4] = {0,0,0,0};
  size_t row = ((size_t)(b * L_ + s * LSEG) * H_ + h) * D_;
  for (int l = 0; l < LSEG; ++l) {
    const float* R = Q + l * 256;
    float2 vv = *(const float2*)(R + e * 8 + 4);
    float ytr = 0.f, yti = 0.f;
    float2 qpv[4];
#pragma unroll
    for (int j = 0; j < 4; ++j) {
      const int d = dg + 8 * j;
      float4 qk = *(const float4*)(R + d * 8);
      float2 aa = *(const float2*)(R + d * 8 + 6);
      float nPr = aa.x * Pr[j] - aa.y * Pi[j];
      float nPi = aa.x * Pi[j] + aa.y * Pr[j];
      Pr[j] = nPr; Pi[j] = nPi;
      qpv[j].x = qk.x * nPr - qk.y * nPi;
      qpv[j].y = qk.x * nPi + qk.y * nPr;
      float kvr = qk.z * vv.x - qk.w * vv.y;
      float kvi = qk.z * vv.y + qk.w * vv.x;
      float nhr = aa.x * hr[j] - aa.y * hi[j] + kvr;
      float nhi = aa.x * hi[j] + aa.y * hr[j] + kvi;
      hr[j] = nhr; hi[j] = nhi;
      ytr += qk.x * nhr - qk.y * nhi;
      yti += qk.x * nhi + qk.y * nhr;
    }
    ytr += __shfl_down(ytr, 4); yti += __shfl_down(yti, 4);
    ytr += __shfl_down(ytr, 2); yti += __shfl_down(yti, 2);
    ytr += __shfl_down(ytr, 1); yti += __shfl_down(yti, 1);
    if (dg == 0)
      *(float2*)(y_loc + (row + e) * 2) = make_float2(ytr, yti);
    if (t < 8) {   // wave 0, eh==0: lanes 0..7 hold all d's qp
#pragma unroll
      for (int j = 0; j < 4; ++j)
        *(float2*)(qP + (row + dg + 8 * j) * 2) = qpv[j];
    }
    row += H_ * D_;
  }
  const size_t segb = (size_t)seg * D_;
  if (t < 8) {
#pragma unroll
    for (int j = 0; j < 4; ++j)
      *(float2*)(Aseg + (segb + dg + 8 * j) * 2) = make_float2(Pr[j], Pi[j]);
  }
#pragma unroll
  for (int j = 0; j < 4; ++j)
    *(float2*)(Hfin + ((segb + dg + 8 * j) * D_ + e) * 2) = make_float2(hr[j], hi[j]);
}

// ---------------- Pass 2: combine segments (bh x e-quarter WGs) ------------
__global__ __launch_bounds__(256) void seg_combine(const float* __restrict__ h0re,
                                                   const float* __restrict__ h0im,
                                                   const float* __restrict__ Aseg,
                                                   const float* __restrict__ Hfin,
                                                   float* __restrict__ Hc) {
  const int bh = blockIdx.x >> 2;
  const int eq = blockIdx.x & 3;
  const int h = bh & (H_ - 1);
  const int t = threadIdx.x;
  const int d = t >> 3;
  const int e = eq * 8 + (t & 7);
  float cr = h0re[((size_t)h * D_ + d) * D_ + e];
  float ci = h0im[((size_t)h * D_ + d) * D_ + e];
  size_t idx = ((size_t)bh * NSEG * D_ + d) * D_ + e;   // advances by D_*D_
  size_t aidx = (size_t)bh * NSEG * D_ + d;             // advances by D_
  float2 A0 = *(const float2*)(Aseg + aidx * 2);
  float2 F0 = *(const float2*)(Hfin + idx * 2);
  for (int s = 0; s < NSEG; ++s) {
    float2 A1, F1;
    if (s + 1 < NSEG) {
      A1 = *(const float2*)(Aseg + (aidx + D_) * 2);
      F1 = *(const float2*)(Hfin + (idx + D_ * D_) * 2);
    }
    *(float2*)(Hc + idx * 2) = make_float2(cr, ci);
    float nr = A0.x * cr - A0.y * ci + F0.x;
    float ni = A0.x * ci + A0.y * cr + F0.y;
    cr = nr; ci = ni;
    A0 = A1; F0 = F1;
    idx += D_ * D_; aidx += D_;
  }
}

// ---------------- Pass 3: y += qP @ Hcarry; emit y2 (bf16) ----------------
__global__ __launch_bounds__(256) void y_correct(const float* __restrict__ y_loc,
                                                 const float* __restrict__ qP,
                                                 const float* __restrict__ Hc,
                                                 bf16_t* __restrict__ y2b) {
  __shared__ __align__(16) float Hs[D_ * D_ * 2];   // 8 KB
  const int seg = blockIdx.x;
  const int s = seg & (NSEG - 1);
  const int bh = seg >> 6;
  const int h = bh & (H_ - 1), b = bh >> 3;
  const int t = threadIdx.x;
  const float4* src = (const float4*)(Hc + (size_t)seg * (D_ * D_ * 2));
  ((float4*)Hs)[t] = src[t];
  ((float4*)Hs)[t + 256] = src[t + 256];
  __syncthreads();
  const int l = t >> 4;            // 0..15
  const int ep = (t & 15) * 2;     // 2 e per thread
  const int lg = s * LSEG + l;
  const size_t rowc = ((size_t)(b * L_ + lg) * H_ + h) * D_;
  const float* qpr = qP + rowc * 2;
  float4 y0 = *(const float4*)(y_loc + (rowc + ep) * 2);
  float ac_r[2] = {y0.x, y0.z}, ac_i[2] = {y0.y, y0.w};
#pragma unroll 4
  for (int d = 0; d < D_; ++d) {
    float2 p = *(const float2*)(qpr + d * 2);
    float4 hv = *(const float4*)&Hs[(d * D_ + ep) * 2];
    ac_r[0] += p.x * hv.x - p.y * hv.y; ac_i[0] += p.x * hv.y + p.y * hv.x;
    ac_r[1] += p.x * hv.z - p.y * hv.w; ac_i[1] += p.x * hv.w + p.y * hv.z;
  }
  union { bf16_t bv[4]; uint2 q; } pk;
  pk.bv[0] = (bf16_t)ac_r[0]; pk.bv[1] = (bf16_t)ac_i[0];
  pk.bv[2] = (bf16_t)ac_r[1]; pk.bv[3] = (bf16_t)ac_i[1];
  *(uint2*)(y2b + (size_t)(b * L_ + lg) * (H_ * D_ * 2) + (h * D_ + ep) * 2) = pk.q;
}

// ---------------- launcher ------------------------------------------------
extern "C" void kernel_launch(void* const* d_in, const int* in_sizes, int n_in,
                              void* d_out, int out_size, void* d_ws, size_t ws_size,
                              hipStream_t stream) {
  const float* x      = (const float*)d_in[0];
  const float* W_in   = (const float*)d_in[1];
  const float* b_in   = (const float*)d_in[2];
  const float* W_qkva = (const float*)d_in[3];
  const float* b_qkva = (const float*)d_in[4];
  const float* W_y    = (const float*)d_in[5];
  const float* b_y    = (const float*)d_in[6];
  const float* W_out  = (const float*)d_in[7];
  const float* b_out  = (const float*)d_in[8];
  const float* h0re   = (const float*)d_in[9];
  const float* h0im   = (const float*)d_in[10];

  char* w = (char*)d_ws;
  const size_t MB = 1ull << 20;
  bf16_t* Wb_in   = (bf16_t*)(w + 0*MB);    // 2 MB
  bf16_t* Wb_qkva = (bf16_t*)(w + 2*MB);    // 4 MB
  bf16_t* Wb_y    = (bf16_t*)(w + 6*MB);    // 1 MB
  bf16_t* Wb_out  = (bf16_t*)(w + 7*MB);    // 2 MB
  bf16_t* xb      = (bf16_t*)(w + 9*MB);    // 8 MB (dead after GEMM1)
  float*  qP      = (float*) (w + 9*MB);    // 8 MB (overlay xb)
  bf16_t* u       = (bf16_t*)(w + 17*MB);   // 8 MB (dead after GEMM2)
  float*  y_loc   = (float*) (w + 17*MB);   // 8 MB (overlay u)
  float*  qkvaT   = (float*) (w + 25*MB);   // 32 MB [b,h,l,256] (dead after scan)
  float*  Hc      = (float*) (w + 25*MB);   // 16 MB (overlay qkvaT)
  bf16_t* y2b     = (bf16_t*)(w + 41*MB);   // 4 MB (overlay qkvaT)
  bf16_t* z       = (bf16_t*)(w + 45*MB);   // 8 MB (overlay qkvaT)
  float*  Aseg    = (float*) (w + 57*MB);   // 0.5 MB
  float*  Hfin    = (float*) (w + 58*MB);   // 16 MB -> total 74 MB

  cvt_all<<<8704, 256, 0, stream>>>(x, W_in, W_qkva, W_y, W_out,
                                    xb, Wb_in, Wb_qkva, Wb_y, Wb_out);

  // u = silu(x @ W_in^T + b_in)                          512 blocks
  gemm_nt<64,1,1,0,0><<<dim3(32, 16), 256, 0, stream>>>(xb, Wb_in, b_in, u, 4096, 1024, 1024);
  // qkvaT = gate(u @ W_qkva^T + b_qkva), transposed store  512 blocks
  gemm_nt<128,0,0,1,1><<<dim3(32, 16), 256, 0, stream>>>(u, Wb_qkva, b_qkva, qkvaT, 4096, 2048, 1024);
  // recurrence
  scan_seg   <<<2048, 256, 0, stream>>>(qkvaT, y_loc, qP, Aseg, Hfin);
  seg_combine<<<128,  256, 0, stream>>>(h0re, h0im, Aseg, Hfin, Hc);
  y_correct  <<<2048, 256, 0, stream>>>(y_loc, qP, Hc, y2b);
  // z = silu(y2 @ W_y^T + b_y)                           512 blocks
  gemm_nt<64,1,1,0,0><<<dim3(32, 16), 256, 0, stream>>>(y2b, Wb_y, b_y, z, 4096, 1024, 512);
  // out = z @ W_out^T + b_out                            512 blocks
  gemm_nt<64,0,0,0,0><<<dim3(32, 16), 256, 0, stream>>>(z, Wb_out, b_out, (float*)d_out, 4096, 1024, 1024);
}

// Round 7
// 229.698 us; speedup vs baseline: 1.7163x; 1.0226x over previous
//
#include <hip/hip_runtime.h>

#define B_ 4
#define L_ 1024
#define DIM_ 1024
#define H_ 8
#define D_ 32
#define LSEG 16
#define NSEG (L_/LSEG)   // 64

typedef __bf16 bf16_t;
typedef __bf16 bf16x8 __attribute__((ext_vector_type(8)));
typedef float f32x4 __attribute__((ext_vector_type(4)));

__device__ __forceinline__ void gload_lds16(const bf16_t* g, bf16_t* l) {
  __builtin_amdgcn_global_load_lds((const __attribute__((address_space(1))) void*)g,
                                   (__attribute__((address_space(3))) void*)l, 16, 0, 0);
}
__device__ __forceinline__ void gload_lds16f(const float* g, float* l) {
  __builtin_amdgcn_global_load_lds((const __attribute__((address_space(1))) void*)g,
                                   (__attribute__((address_space(3))) void*)l, 16, 0, 0);
}

// ---------------- merged f32 -> bf16 converts (5 regions, 1 launch) --------
__global__ __launch_bounds__(256) void cvt_all(const float* __restrict__ x,
                                               const float* __restrict__ w1,
                                               const float* __restrict__ w2,
                                               const float* __restrict__ w3,
                                               const float* __restrict__ w4,
                                               bf16_t* __restrict__ ox,
                                               bf16_t* __restrict__ o1,
                                               bf16_t* __restrict__ o2,
                                               bf16_t* __restrict__ o3,
                                               bf16_t* __restrict__ o4) {
  int g = blockIdx.x;
  const float* in; bf16_t* out; int i;
  if      (g < 4096) { in = x;  out = ox; i = g * 256 + threadIdx.x; }
  else if (g < 5120) { in = w1; out = o1; i = (g - 4096) * 256 + threadIdx.x; }
  else if (g < 7168) { in = w2; out = o2; i = (g - 5120) * 256 + threadIdx.x; }
  else if (g < 7680) { in = w3; out = o3; i = (g - 7168) * 256 + threadIdx.x; }
  else               { in = w4; out = o4; i = (g - 7680) * 256 + threadIdx.x; }
  float4 v = ((const float4*)in)[i];
  union { bf16_t b[4]; unsigned long long q; } pk;
  pk.b[0] = (bf16_t)v.x; pk.b[1] = (bf16_t)v.y;
  pk.b[2] = (bf16_t)v.z; pk.b[3] = (bf16_t)v.w;
  ((unsigned long long*)out)[i] = pk.q;
}

// ---------------- NT GEMM, BM=128 BN=128 BK=64 (for GEMM2) -----------------
// XOR bank swizzle: 16B slot s of row r holds global slot s^(r&7).
// GATE=1: cols with (c&7)>=6 are (a_re,a_im) pairs -> unit-rot*sigmoid gate
// via shfl_xor(1). TRANS=1: scatter-store C to [b,h,l,256] f32 layout.
template<int BN, int ACT, int OUTBF, int GATE, int TRANS>
__global__ __launch_bounds__(256) void gemm_nt(const bf16_t* __restrict__ A,
                                               const bf16_t* __restrict__ Bm,
                                               const float* __restrict__ bias,
                                               void* __restrict__ Cout,
                                               int M, int N, int K) {
  constexpr int NI = BN / 32;
  constexpr int ISS_B = BN / 32;
  __shared__ __align__(16) bf16_t As[128 * 64];
  __shared__ __align__(16) bf16_t Bs[BN * 64];
  const int t = threadIdx.x;
  const int wid = t >> 6, lane = t & 63;
  const int wr = wid >> 1, wc = wid & 1;
  const int lr = lane & 15, lq = lane >> 4;
  const int bm = blockIdx.x, bn = blockIdx.y;
  const int rA = wid * 32 + (lane >> 3);
  const int rB = wid * (BN / 4) + (lane >> 3);
  const int c8 = (((lane & 7) ^ ((lane >> 3) & 7))) * 8;
  const bf16_t* Ag = A + (size_t)(bm * 128 + rA) * K + c8;
  const bf16_t* Bg = Bm + (size_t)(bn * BN + rB) * K + c8;
  bf16_t* AsW = As + (wid * 32) * 64;
  bf16_t* BsW = Bs + (wid * (BN / 4)) * 64;
  f32x4 acc[4][NI] = {};
  for (int k0 = 0; k0 < K; k0 += 64) {
#pragma unroll
    for (int j = 0; j < 4; ++j)
      gload_lds16(Ag + (size_t)j * 8 * K, AsW + j * 8 * 64);
#pragma unroll
    for (int j = 0; j < ISS_B; ++j)
      gload_lds16(Bg + (size_t)j * 8 * K, BsW + j * 8 * 64);
    Ag += 64; Bg += 64;
    __syncthreads();
#pragma unroll
    for (int ks = 0; ks < 2; ++ks) {
      const int sg = ks * 4 + lq;
      const int sl = (sg ^ (lr & 7)) * 8;
      bf16x8 af[4], bfv[NI];
#pragma unroll
      for (int mi = 0; mi < 4; ++mi)
        af[mi] = *(const bf16x8*)&As[(wr * 64 + mi * 16 + lr) * 64 + sl];
#pragma unroll
      for (int ni = 0; ni < NI; ++ni)
        bfv[ni] = *(const bf16x8*)&Bs[(wc * (BN/2) + ni * 16 + lr) * 64 + sl];
#pragma unroll
      for (int mi = 0; mi < 4; ++mi)
#pragma unroll
        for (int ni = 0; ni < NI; ++ni)
          acc[mi][ni] = __builtin_amdgcn_mfma_f32_16x16x32_bf16(af[mi], bfv[ni], acc[mi][ni], 0, 0, 0);
    }
    __syncthreads();
  }
#pragma unroll
  for (int mi = 0; mi < 4; ++mi) {
#pragma unroll
    for (int ni = 0; ni < NI; ++ni) {
      int colg = bn * BN + wc * (BN/2) + ni * 16 + lr;
      float bb = bias[colg];
#pragma unroll
      for (int r = 0; r < 4; ++r) {
        int rowg = bm * 128 + wr * 64 + mi * 16 + lq * 4 + r;
        float v = acc[mi][ni][r] + bb;
        if (ACT == 1) v = v / (1.0f + __expf(-v));
        if (GATE) {
          float wv = __shfl_xor(v, 1);
          if ((colg & 7) >= 6) {
            float m2 = v * v + wv * wv;
            v *= sqrtf(m2) / (1.0f + m2);
          }
        }
        if (TRANS) {
          size_t idx = (((size_t)((rowg >> 10) * 8 + (colg >> 8))) * 1024
                        + (rowg & 1023)) * 256 + (colg & 255);
          ((float*)Cout)[idx] = v;
        } else if (OUTBF) {
          ((bf16_t*)Cout)[(size_t)rowg * N + colg] = (bf16_t)v;
        } else {
          ((float*)Cout)[(size_t)rowg * N + colg] = v;
        }
      }
    }
  }
}

// ---------------- NT GEMM, BM=128 BN=64 BK=128 (GEMM1/3/4) -----------------
// BK=128 halves barrier count: 32 MFMA per barrier-pair, LDS 48KB -> 3 blk/CU.
// Staging: issue j covers 4 rows (64 lanes x 16B = 1KB); lane row = lane>>4,
// slot = lane&15. Swizzle: slot s of row r holds global slot s^(r&15);
// r&15 at staging = wid*4 + (lane>>4) (j adds multiples of 16).
// Frag reads: row&15 == lr, slot sg=ks*4+lq -> LDS slot sg^lr.
template<int ACT, int OUTBF>
__global__ __launch_bounds__(256) void gemm_nt64(const bf16_t* __restrict__ A,
                                                 const bf16_t* __restrict__ Bm,
                                                 const float* __restrict__ bias,
                                                 void* __restrict__ Cout,
                                                 int M, int N, int K) {
  __shared__ __align__(16) bf16_t As[128 * 128];   // 32 KB
  __shared__ __align__(16) bf16_t Bs[64 * 128];    // 16 KB
  const int t = threadIdx.x;
  const int wid = t >> 6, lane = t & 63;
  const int wr = wid >> 1, wc = wid & 1;
  const int lr = lane & 15, lq = lane >> 4;
  const int bm = blockIdx.x, bn = blockIdx.y;
  const int crow = wid * 4 + (lane >> 4);          // staging row (mod 16)
  const int c8 = ((lane & 15) ^ crow) * 8;         // swizzled global col
  const bf16_t* Ag = A + (size_t)(bm * 128 + crow) * K + c8;
  const bf16_t* Bg = Bm + (size_t)(bn * 64 + crow) * K + c8;
  bf16_t* AsW = As + (wid * 4) * 128;
  bf16_t* BsW = Bs + (wid * 4) * 128;
  f32x4 acc[4][2] = {};
  for (int k0 = 0; k0 < K; k0 += 128) {
#pragma unroll
    for (int j = 0; j < 8; ++j)
      gload_lds16(Ag + (size_t)j * 16 * K, AsW + j * 16 * 128);
#pragma unroll
    for (int j = 0; j < 4; ++j)
      gload_lds16(Bg + (size_t)j * 16 * K, BsW + j * 16 * 128);
    Ag += 128; Bg += 128;
    __syncthreads();
#pragma unroll
    for (int ks = 0; ks < 4; ++ks) {
      const int sg = ks * 4 + lq;
      const int sl = (sg ^ lr) * 8;
      bf16x8 af[4], bfv[2];
#pragma unroll
      for (int mi = 0; mi < 4; ++mi)
        af[mi] = *(const bf16x8*)&As[(wr * 64 + mi * 16 + lr) * 128 + sl];
#pragma unroll
      for (int ni = 0; ni < 2; ++ni)
        bfv[ni] = *(const bf16x8*)&Bs[(wc * 32 + ni * 16 + lr) * 128 + sl];
#pragma unroll
      for (int mi = 0; mi < 4; ++mi)
#pragma unroll
        for (int ni = 0; ni < 2; ++ni)
          acc[mi][ni] = __builtin_amdgcn_mfma_f32_16x16x32_bf16(af[mi], bfv[ni], acc[mi][ni], 0, 0, 0);
    }
    __syncthreads();
  }
#pragma unroll
  for (int mi = 0; mi < 4; ++mi) {
#pragma unroll
    for (int ni = 0; ni < 2; ++ni) {
      int colg = bn * 64 + wc * 32 + ni * 16 + lr;
      float bb = bias[colg];
#pragma unroll
      for (int r = 0; r < 4; ++r) {
        int rowg = bm * 128 + wr * 64 + mi * 16 + lq * 4 + r;
        float v = acc[mi][ni][r] + bb;
        if (ACT == 1) v = v / (1.0f + __expf(-v));
        if (OUTBF) ((bf16_t*)Cout)[(size_t)rowg * N + colg] = (bf16_t)v;
        else       ((float*)Cout)[(size_t)rowg * N + colg] = v;
      }
    }
  }
}

// ---------------- Pass 1: scan, 1 block/segment, LDS-staged ----------------
__global__ __launch_bounds__(256) void scan_seg(const float* __restrict__ qkvaT,
                                                float* __restrict__ y_loc,
                                                float* __restrict__ qP,
                                                float* __restrict__ Aseg,
                                                float* __restrict__ Hfin) {
  __shared__ __align__(16) float Q[LSEG * 256];    // 16 KB
  const int t = threadIdx.x;
  const int seg = blockIdx.x;              // [0, 2048)
  const int s = seg & (NSEG - 1);
  const int bh = seg >> 6;                 // NSEG==64
  const int h = bh & (H_ - 1), b = bh >> 3;
  const int wid = t >> 6, lane = t & 63;
  const int dg = lane & 7, eh = lane >> 3;
  const int e = wid * 8 + eh;
  const float* gb = qkvaT + ((size_t)bh * L_ + s * LSEG) * 256;
#pragma unroll
  for (int c = 0; c < 4; ++c)
    gload_lds16f(gb + c * 1024 + t * 4, Q + c * 1024 + wid * 256);
  __syncthreads();
  float hr[4] = {}, hi[4] = {};
  float Pr[4] = {1,1,1,1}, Pi[4] = {0,0,0,0};
  size_t row = ((size_t)(b * L_ + s * LSEG) * H_ + h) * D_;
  for (int l = 0; l < LSEG; ++l) {
    const float* R = Q + l * 256;
    float2 vv = *(const float2*)(R + e * 8 + 4);
    float ytr = 0.f, yti = 0.f;
    float2 qpv[4];
#pragma unroll
    for (int j = 0; j < 4; ++j) {
      const int d = dg + 8 * j;
      float4 qk = *(const float4*)(R + d * 8);
      float2 aa = *(const float2*)(R + d * 8 + 6);
      float nPr = aa.x * Pr[j] - aa.y * Pi[j];
      float nPi = aa.x * Pi[j] + aa.y * Pr[j];
      Pr[j] = nPr; Pi[j] = nPi;
      qpv[j].x = qk.x * nPr - qk.y * nPi;
      qpv[j].y = qk.x * nPi + qk.y * nPr;
      float kvr = qk.z * vv.x - qk.w * vv.y;
      float kvi = qk.z * vv.y + qk.w * vv.x;
      float nhr = aa.x * hr[j] - aa.y * hi[j] + kvr;
      float nhi = aa.x * hi[j] + aa.y * hr[j] + kvi;
      hr[j] = nhr; hi[j] = nhi;
      ytr += qk.x * nhr - qk.y * nhi;
      yti += qk.x * nhi + qk.y * nhr;
    }
    ytr += __shfl_down(ytr, 4); yti += __shfl_down(yti, 4);
    ytr += __shfl_down(ytr, 2); yti += __shfl_down(yti, 2);
    ytr += __shfl_down(ytr, 1); yti += __shfl_down(yti, 1);
    if (dg == 0)
      *(float2*)(y_loc + (row + e) * 2) = make_float2(ytr, yti);
    if (t < 8) {
#pragma unroll
      for (int j = 0; j < 4; ++j)
        *(float2*)(qP + (row + dg + 8 * j) * 2) = qpv[j];
    }
    row += H_ * D_;
  }
  const size_t segb = (size_t)seg * D_;
  if (t < 8) {
#pragma unroll
    for (int j = 0; j < 4; ++j)
      *(float2*)(Aseg + (segb + dg + 8 * j) * 2) = make_float2(Pr[j], Pi[j]);
  }
#pragma unroll
  for (int j = 0; j < 4; ++j)
    *(float2*)(Hfin + ((segb + dg + 8 * j) * D_ + e) * 2) = make_float2(hr[j], hi[j]);
}

// ---------------- Pass 2: combine segments (256 blocks x 128 thr) ----------
// block = bh(32) x eg(8); thread covers d = t>>2 (32), e = eg*4 + (t&3).
__global__ __launch_bounds__(128) void seg_combine(const float* __restrict__ h0re,
                                                   const float* __restrict__ h0im,
                                                   const float* __restrict__ Aseg,
                                                   const float* __restrict__ Hfin,
                                                   float* __restrict__ Hc) {
  const int bh = blockIdx.x >> 3;
  const int eg = blockIdx.x & 7;
  const int h = bh & (H_ - 1);
  const int t = threadIdx.x;
  const int d = t >> 2;
  const int e = eg * 4 + (t & 3);
  float cr = h0re[((size_t)h * D_ + d) * D_ + e];
  float ci = h0im[((size_t)h * D_ + d) * D_ + e];
  size_t idx = ((size_t)bh * NSEG * D_ + d) * D_ + e;   // advances by D_*D_
  size_t aidx = (size_t)bh * NSEG * D_ + d;             // advances by D_
  float2 A0 = *(const float2*)(Aseg + aidx * 2);
  float2 F0 = *(const float2*)(Hfin + idx * 2);
  for (int s = 0; s < NSEG; ++s) {
    float2 A1, F1;
    if (s + 1 < NSEG) {
      A1 = *(const float2*)(Aseg + (aidx + D_) * 2);
      F1 = *(const float2*)(Hfin + (idx + D_ * D_) * 2);
    }
    *(float2*)(Hc + idx * 2) = make_float2(cr, ci);
    float nr = A0.x * cr - A0.y * ci + F0.x;
    float ni = A0.x * ci + A0.y * cr + F0.y;
    cr = nr; ci = ni;
    A0 = A1; F0 = F1;
    idx += D_ * D_; aidx += D_;
  }
}

// ---------------- Pass 3: y += qP @ Hcarry; emit y2 (bf16) ----------------
__global__ __launch_bounds__(256) void y_correct(const float* __restrict__ y_loc,
                                                 const float* __restrict__ qP,
                                                 const float* __restrict__ Hc,
                                                 bf16_t* __restrict__ y2b) {
  __shared__ __align__(16) float Hs[D_ * D_ * 2];   // 8 KB
  const int seg = blockIdx.x;
  const int s = seg & (NSEG - 1);
  const int bh = seg >> 6;
  const int h = bh & (H_ - 1), b = bh >> 3;
  const int t = threadIdx.x;
  const float4* src = (const float4*)(Hc + (size_t)seg * (D_ * D_ * 2));
  ((float4*)Hs)[t] = src[t];
  ((float4*)Hs)[t + 256] = src[t + 256];
  __syncthreads();
  const int l = t >> 4;            // 0..15
  const int ep = (t & 15) * 2;     // 2 e per thread
  const int lg = s * LSEG + l;
  const size_t rowc = ((size_t)(b * L_ + lg) * H_ + h) * D_;
  const float* qpr = qP + rowc * 2;
  float4 y0 = *(const float4*)(y_loc + (rowc + ep) * 2);
  float ac_r[2] = {y0.x, y0.z}, ac_i[2] = {y0.y, y0.w};
#pragma unroll 4
  for (int d = 0; d < D_; ++d) {
    float2 p = *(const float2*)(qpr + d * 2);
    float4 hv = *(const float4*)&Hs[(d * D_ + ep) * 2];
    ac_r[0] += p.x * hv.x - p.y * hv.y; ac_i[0] += p.x * hv.y + p.y * hv.x;
    ac_r[1] += p.x * hv.z - p.y * hv.w; ac_i[1] += p.x * hv.w + p.y * hv.z;
  }
  union { bf16_t bv[4]; uint2 q; } pk;
  pk.bv[0] = (bf16_t)ac_r[0]; pk.bv[1] = (bf16_t)ac_i[0];
  pk.bv[2] = (bf16_t)ac_r[1]; pk.bv[3] = (bf16_t)ac_i[1];
  *(uint2*)(y2b + (size_t)(b * L_ + lg) * (H_ * D_ * 2) + (h * D_ + ep) * 2) = pk.q;
}

// ---------------- launcher ------------------------------------------------
extern "C" void kernel_launch(void* const* d_in, const int* in_sizes, int n_in,
                              void* d_out, int out_size, void* d_ws, size_t ws_size,
                              hipStream_t stream) {
  const float* x      = (const float*)d_in[0];
  const float* W_in   = (const float*)d_in[1];
  const float* b_in   = (const float*)d_in[2];
  const float* W_qkva = (const float*)d_in[3];
  const float* b_qkva = (const float*)d_in[4];
  const float* W_y    = (const float*)d_in[5];
  const float* b_y    = (const float*)d_in[6];
  const float* W_out  = (const float*)d_in[7];
  const float* b_out  = (const float*)d_in[8];
  const float* h0re   = (const float*)d_in[9];
  const float* h0im   = (const float*)d_in[10];

  char* w = (char*)d_ws;
  const size_t MB = 1ull << 20;
  bf16_t* Wb_in   = (bf16_t*)(w + 0*MB);    // 2 MB
  bf16_t* Wb_qkva = (bf16_t*)(w + 2*MB);    // 4 MB
  bf16_t* Wb_y    = (bf16_t*)(w + 6*MB);    // 1 MB
  bf16_t* Wb_out  = (bf16_t*)(w + 7*MB);    // 2 MB
  bf16_t* xb      = (bf16_t*)(w + 9*MB);    // 8 MB (dead after GEMM1)
  float*  qP      = (float*) (w + 9*MB);    // 8 MB (overlay xb)
  bf16_t* u       = (bf16_t*)(w + 17*MB);   // 8 MB (dead after GEMM2)
  float*  y_loc   = (float*) (w + 17*MB);   // 8 MB (overlay u)
  float*  qkvaT   = (float*) (w + 25*MB);   // 32 MB [b,h,l,256] (dead after scan)
  float*  Hc      = (float*) (w + 25*MB);   // 16 MB (overlay qkvaT)
  bf16_t* y2b     = (bf16_t*)(w + 41*MB);   // 4 MB (overlay qkvaT)
  bf16_t* z       = (bf16_t*)(w + 45*MB);   // 8 MB (overlay qkvaT)
  float*  Aseg    = (float*) (w + 57*MB);   // 0.5 MB
  float*  Hfin    = (float*) (w + 58*MB);   // 16 MB -> total 74 MB

  cvt_all<<<8704, 256, 0, stream>>>(x, W_in, W_qkva, W_y, W_out,
                                    xb, Wb_in, Wb_qkva, Wb_y, Wb_out);

  // u = silu(x @ W_in^T + b_in)                          512 blocks, BK=128
  gemm_nt64<1,1><<<dim3(32, 16), 256, 0, stream>>>(xb, Wb_in, b_in, u, 4096, 1024, 1024);
  // qkvaT = gate(u @ W_qkva^T + b_qkva), transposed store  512 blocks
  gemm_nt<128,0,0,1,1><<<dim3(32, 16), 256, 0, stream>>>(u, Wb_qkva, b_qkva, qkvaT, 4096, 2048, 1024);
  // recurrence
  scan_seg   <<<2048, 256, 0, stream>>>(qkvaT, y_loc, qP, Aseg, Hfin);
  seg_combine<<<256,  128, 0, stream>>>(h0re, h0im, Aseg, Hfin, Hc);
  y_correct  <<<2048, 256, 0, stream>>>(y_loc, qP, Hc, y2b);
  // z = silu(y2 @ W_y^T + b_y)                           512 blocks, BK=128
  gemm_nt64<1,1><<<dim3(32, 16), 256, 0, stream>>>(y2b, Wb_y, b_y, z, 4096, 1024, 512);
  // out = z @ W_out^T + b_out                            512 blocks, BK=128
  gemm_nt64<0,0><<<dim3(32, 16), 256, 0, stream>>>(z, Wb_out, b_out, (float*)d_out, 4096, 1024, 1024);
}

// Round 8
// 226.240 us; speedup vs baseline: 1.7425x; 1.0153x over previous
//
#include <hip/hip_runtime.h>

#define B_ 4
#define L_ 1024
#define DIM_ 1024
#define H_ 8
#define D_ 32
#define LSEG 16
#define NSEG (L_/LSEG)   // 64

typedef __bf16 bf16_t;
typedef __bf16 bf16x8 __attribute__((ext_vector_type(8)));
typedef float f32x4 __attribute__((ext_vector_type(4)));

__device__ __forceinline__ void gload_lds16(const bf16_t* g, bf16_t* l) {
  __builtin_amdgcn_global_load_lds((const __attribute__((address_space(1))) void*)g,
                                   (__attribute__((address_space(3))) void*)l, 16, 0, 0);
}
__device__ __forceinline__ void gload_lds16f(const float* g, float* l) {
  __builtin_amdgcn_global_load_lds((const __attribute__((address_space(1))) void*)g,
                                   (__attribute__((address_space(3))) void*)l, 16, 0, 0);
}

// ---------------- merged f32 -> bf16 converts (5 regions, 1 launch) --------
__global__ __launch_bounds__(256) void cvt_all(const float* __restrict__ x,
                                               const float* __restrict__ w1,
                                               const float* __restrict__ w2,
                                               const float* __restrict__ w3,
                                               const float* __restrict__ w4,
                                               bf16_t* __restrict__ ox,
                                               bf16_t* __restrict__ o1,
                                               bf16_t* __restrict__ o2,
                                               bf16_t* __restrict__ o3,
                                               bf16_t* __restrict__ o4) {
  int g = blockIdx.x;
  const float* in; bf16_t* out; int i;
  if      (g < 4096) { in = x;  out = ox; i = g * 256 + threadIdx.x; }
  else if (g < 5120) { in = w1; out = o1; i = (g - 4096) * 256 + threadIdx.x; }
  else if (g < 7168) { in = w2; out = o2; i = (g - 5120) * 256 + threadIdx.x; }
  else if (g < 7680) { in = w3; out = o3; i = (g - 7168) * 256 + threadIdx.x; }
  else               { in = w4; out = o4; i = (g - 7680) * 256 + threadIdx.x; }
  float4 v = ((const float4*)in)[i];
  union { bf16_t b[4]; unsigned long long q; } pk;
  pk.b[0] = (bf16_t)v.x; pk.b[1] = (bf16_t)v.y;
  pk.b[2] = (bf16_t)v.z; pk.b[3] = (bf16_t)v.w;
  ((unsigned long long*)out)[i] = pk.q;
}

// ---------------- NT GEMM, BM=128 BN=128 BK=64 (GEMM2) ---------------------
// XOR bank swizzle: 16B slot s of row r holds global slot s^(r&7).
// GATE=1: cols with (c&7)>=6 are (a_re,a_im) pairs -> unit-rot*sigmoid gate
// via shfl_xor(1). Plain coalesced store (f32 or bf16).
template<int BN, int ACT, int OUTBF, int GATE>
__global__ __launch_bounds__(256) void gemm_nt(const bf16_t* __restrict__ A,
                                               const bf16_t* __restrict__ Bm,
                                               const float* __restrict__ bias,
                                               void* __restrict__ Cout,
                                               int M, int N, int K) {
  constexpr int NI = BN / 32;
  constexpr int ISS_B = BN / 32;
  __shared__ __align__(16) bf16_t As[128 * 64];
  __shared__ __align__(16) bf16_t Bs[BN * 64];
  const int t = threadIdx.x;
  const int wid = t >> 6, lane = t & 63;
  const int wr = wid >> 1, wc = wid & 1;
  const int lr = lane & 15, lq = lane >> 4;
  const int bm = blockIdx.x, bn = blockIdx.y;
  const int rA = wid * 32 + (lane >> 3);
  const int rB = wid * (BN / 4) + (lane >> 3);
  const int c8 = (((lane & 7) ^ ((lane >> 3) & 7))) * 8;
  const bf16_t* Ag = A + (size_t)(bm * 128 + rA) * K + c8;
  const bf16_t* Bg = Bm + (size_t)(bn * BN + rB) * K + c8;
  bf16_t* AsW = As + (wid * 32) * 64;
  bf16_t* BsW = Bs + (wid * (BN / 4)) * 64;
  f32x4 acc[4][NI] = {};
  for (int k0 = 0; k0 < K; k0 += 64) {
#pragma unroll
    for (int j = 0; j < 4; ++j)
      gload_lds16(Ag + (size_t)j * 8 * K, AsW + j * 8 * 64);
#pragma unroll
    for (int j = 0; j < ISS_B; ++j)
      gload_lds16(Bg + (size_t)j * 8 * K, BsW + j * 8 * 64);
    Ag += 64; Bg += 64;
    __syncthreads();
#pragma unroll
    for (int ks = 0; ks < 2; ++ks) {
      const int sg = ks * 4 + lq;
      const int sl = (sg ^ (lr & 7)) * 8;
      bf16x8 af[4], bfv[NI];
#pragma unroll
      for (int mi = 0; mi < 4; ++mi)
        af[mi] = *(const bf16x8*)&As[(wr * 64 + mi * 16 + lr) * 64 + sl];
#pragma unroll
      for (int ni = 0; ni < NI; ++ni)
        bfv[ni] = *(const bf16x8*)&Bs[(wc * (BN/2) + ni * 16 + lr) * 64 + sl];
#pragma unroll
      for (int mi = 0; mi < 4; ++mi)
#pragma unroll
        for (int ni = 0; ni < NI; ++ni)
          acc[mi][ni] = __builtin_amdgcn_mfma_f32_16x16x32_bf16(af[mi], bfv[ni], acc[mi][ni], 0, 0, 0);
    }
    __syncthreads();
  }
#pragma unroll
  for (int mi = 0; mi < 4; ++mi) {
#pragma unroll
    for (int ni = 0; ni < NI; ++ni) {
      int colg = bn * BN + wc * (BN/2) + ni * 16 + lr;
      float bb = bias[colg];
#pragma unroll
      for (int r = 0; r < 4; ++r) {
        int rowg = bm * 128 + wr * 64 + mi * 16 + lq * 4 + r;
        float v = acc[mi][ni][r] + bb;
        if (ACT == 1) v = v / (1.0f + __expf(-v));
        if (GATE) {
          float wv = __shfl_xor(v, 1);
          if ((colg & 7) >= 6) {
            float m2 = v * v + wv * wv;
            v *= sqrtf(m2) / (1.0f + m2);
          }
        }
        if (OUTBF) ((bf16_t*)Cout)[(size_t)rowg * N + colg] = (bf16_t)v;
        else       ((float*)Cout)[(size_t)rowg * N + colg] = v;
      }
    }
  }
}

// ---------------- NT GEMM, BM=128 BN=64 BK=128 (GEMM1/3/4) -----------------
template<int ACT, int OUTBF>
__global__ __launch_bounds__(256) void gemm_nt64(const bf16_t* __restrict__ A,
                                                 const bf16_t* __restrict__ Bm,
                                                 const float* __restrict__ bias,
                                                 void* __restrict__ Cout,
                                                 int M, int N, int K) {
  __shared__ __align__(16) bf16_t As[128 * 128];   // 32 KB
  __shared__ __align__(16) bf16_t Bs[64 * 128];    // 16 KB
  const int t = threadIdx.x;
  const int wid = t >> 6, lane = t & 63;
  const int wr = wid >> 1, wc = wid & 1;
  const int lr = lane & 15, lq = lane >> 4;
  const int bm = blockIdx.x, bn = blockIdx.y;
  const int crow = wid * 4 + (lane >> 4);          // staging row (mod 16)
  const int c8 = ((lane & 15) ^ crow) * 8;         // swizzled global col
  const bf16_t* Ag = A + (size_t)(bm * 128 + crow) * K + c8;
  const bf16_t* Bg = Bm + (size_t)(bn * 64 + crow) * K + c8;
  bf16_t* AsW = As + (wid * 4) * 128;
  bf16_t* BsW = Bs + (wid * 4) * 128;
  f32x4 acc[4][2] = {};
  for (int k0 = 0; k0 < K; k0 += 128) {
#pragma unroll
    for (int j = 0; j < 8; ++j)
      gload_lds16(Ag + (size_t)j * 16 * K, AsW + j * 16 * 128);
#pragma unroll
    for (int j = 0; j < 4; ++j)
      gload_lds16(Bg + (size_t)j * 16 * K, BsW + j * 16 * 128);
    Ag += 128; Bg += 128;
    __syncthreads();
#pragma unroll
    for (int ks = 0; ks < 4; ++ks) {
      const int sg = ks * 4 + lq;
      const int sl = (sg ^ lr) * 8;
      bf16x8 af[4], bfv[2];
#pragma unroll
      for (int mi = 0; mi < 4; ++mi)
        af[mi] = *(const bf16x8*)&As[(wr * 64 + mi * 16 + lr) * 128 + sl];
#pragma unroll
      for (int ni = 0; ni < 2; ++ni)
        bfv[ni] = *(const bf16x8*)&Bs[(wc * 32 + ni * 16 + lr) * 128 + sl];
#pragma unroll
      for (int mi = 0; mi < 4; ++mi)
#pragma unroll
        for (int ni = 0; ni < 2; ++ni)
          acc[mi][ni] = __builtin_amdgcn_mfma_f32_16x16x32_bf16(af[mi], bfv[ni], acc[mi][ni], 0, 0, 0);
    }
    __syncthreads();
  }
#pragma unroll
  for (int mi = 0; mi < 4; ++mi) {
#pragma unroll
    for (int ni = 0; ni < 2; ++ni) {
      int colg = bn * 64 + wc * 32 + ni * 16 + lr;
      float bb = bias[colg];
#pragma unroll
      for (int r = 0; r < 4; ++r) {
        int rowg = bm * 128 + wr * 64 + mi * 16 + lq * 4 + r;
        float v = acc[mi][ni][r] + bb;
        if (ACT == 1) v = v / (1.0f + __expf(-v));
        if (OUTBF) ((bf16_t*)Cout)[(size_t)rowg * N + colg] = (bf16_t)v;
        else       ((float*)Cout)[(size_t)rowg * N + colg] = v;
      }
    }
  }
}

// ---------------- Pass 1: scan, 1 block/segment, LDS-staged ----------------
// qkva natural layout [b,l,h,d,c] f32. A segment's 16 rows (1 KB each, 8 KB
// apart) are staged with 16 per-row global_load_lds issues (wave-uniform
// LDS dest, 64 lanes x 16B = 1 KB dense). Then 16 serial steps from LDS.
__global__ __launch_bounds__(256) void scan_seg(const float* __restrict__ qkva,
                                                float* __restrict__ y_loc,
                                                float* __restrict__ qP,
                                                float* __restrict__ Aseg,
                                                float* __restrict__ Hfin) {
  __shared__ __align__(16) float Q[LSEG * 256];    // 16 KB
  const int t = threadIdx.x;
  const int seg = blockIdx.x;              // [0, 2048)
  const int s = seg & (NSEG - 1);
  const int bh = seg >> 6;                 // NSEG==64
  const int h = bh & (H_ - 1), b = bh >> 3;
  const int wid = t >> 6, lane = t & 63;
  const int dg = lane & 7, eh = lane >> 3;
  const int e = wid * 8 + eh;
  const float* gb = qkva + ((size_t)(b * L_ + s * LSEG) * H_ + h) * 256;
#pragma unroll
  for (int j = 0; j < 4; ++j) {
    const int l = wid * 4 + j;             // wave-uniform row index
    gload_lds16f(gb + (size_t)l * (H_ * 256) + lane * 4, Q + l * 256);
  }
  __syncthreads();
  float hr[4] = {}, hi[4] = {};
  float Pr[4] = {1,1,1,1}, Pi[4] = {0,0,0,0};
  size_t row = ((size_t)(b * L_ + s * LSEG) * H_ + h) * D_;
  for (int l = 0; l < LSEG; ++l) {
    const float* R = Q + l * 256;
    float2 vv = *(const float2*)(R + e * 8 + 4);
    float ytr = 0.f, yti = 0.f;
    float2 qpv[4];
#pragma unroll
    for (int j = 0; j < 4; ++j) {
      const int d = dg + 8 * j;
      float4 qk = *(const float4*)(R + d * 8);
      float2 aa = *(const float2*)(R + d * 8 + 6);
      float nPr = aa.x * Pr[j] - aa.y * Pi[j];
      float nPi = aa.x * Pi[j] + aa.y * Pr[j];
      Pr[j] = nPr; Pi[j] = nPi;
      qpv[j].x = qk.x * nPr - qk.y * nPi;
      qpv[j].y = qk.x * nPi + qk.y * nPr;
      float kvr = qk.z * vv.x - qk.w * vv.y;
      float kvi = qk.z * vv.y + qk.w * vv.x;
      float nhr = aa.x * hr[j] - aa.y * hi[j] + kvr;
      float nhi = aa.x * hi[j] + aa.y * hr[j] + kvi;
      hr[j] = nhr; hi[j] = nhi;
      ytr += qk.x * nhr - qk.y * nhi;
      yti += qk.x * nhi + qk.y * nhr;
    }
    ytr += __shfl_down(ytr, 4); yti += __shfl_down(yti, 4);
    ytr += __shfl_down(ytr, 2); yti += __shfl_down(yti, 2);
    ytr += __shfl_down(ytr, 1); yti += __shfl_down(yti, 1);
    if (dg == 0)
      *(float2*)(y_loc + (row + e) * 2) = make_float2(ytr, yti);
    if (t < 8) {
#pragma unroll
      for (int j = 0; j < 4; ++j)
        *(float2*)(qP + (row + dg + 8 * j) * 2) = qpv[j];
    }
    row += H_ * D_;
  }
  const size_t segb = (size_t)seg * D_;
  if (t < 8) {
#pragma unroll
    for (int j = 0; j < 4; ++j)
      *(float2*)(Aseg + (segb + dg + 8 * j) * 2) = make_float2(Pr[j], Pi[j]);
  }
#pragma unroll
  for (int j = 0; j < 4; ++j)
    *(float2*)(Hfin + ((segb + dg + 8 * j) * D_ + e) * 2) = make_float2(hr[j], hi[j]);
}

// ---------------- Pass 2: combine segments, depth-8 prefetch ---------------
// block = bh(32) x eg(8); thread covers d = t>>2, e = eg*4 + (t&3).
// The 64-step serial chain is latency-bound on Hfin loads (4KB stride);
// a ring of 8 in-flight loads hides ~8x of the ~400-900 cyc miss latency.
__global__ __launch_bounds__(128) void seg_combine(const float* __restrict__ h0re,
                                                   const float* __restrict__ h0im,
                                                   const float* __restrict__ Aseg,
                                                   const float* __restrict__ Hfin,
                                                   float* __restrict__ Hc) {
  const int bh = blockIdx.x >> 3;
  const int eg = blockIdx.x & 7;
  const int h = bh & (H_ - 1);
  const int t = threadIdx.x;
  const int d = t >> 2;
  const int e = eg * 4 + (t & 3);
  float cr = h0re[((size_t)h * D_ + d) * D_ + e];
  float ci = h0im[((size_t)h * D_ + d) * D_ + e];
  const size_t idx0  = ((size_t)bh * NSEG * D_ + d) * D_ + e;  // +s*D_*D_
  const size_t aidx0 = (size_t)bh * NSEG * D_ + d;             // +s*D_
  float2 Ab[8], Fb[8];
#pragma unroll
  for (int p = 0; p < 8; ++p) {
    Ab[p] = *(const float2*)(Aseg + (aidx0 + (size_t)p * D_) * 2);
    Fb[p] = *(const float2*)(Hfin + (idx0 + (size_t)p * D_ * D_) * 2);
  }
  for (int so = 0; so < NSEG; so += 8) {
#pragma unroll
    for (int p = 0; p < 8; ++p) {
      const int s = so + p;
      float2 A0 = Ab[p], F0 = Fb[p];
      if (so + 8 < NSEG) {
        Ab[p] = *(const float2*)(Aseg + (aidx0 + (size_t)(s + 8) * D_) * 2);
        Fb[p] = *(const float2*)(Hfin + (idx0 + (size_t)(s + 8) * D_ * D_) * 2);
      }
      *(float2*)(Hc + (idx0 + (size_t)s * D_ * D_) * 2) = make_float2(cr, ci);
      float nr = A0.x * cr - A0.y * ci + F0.x;
      float ni = A0.x * ci + A0.y * cr + F0.y;
      cr = nr; ci = ni;
    }
  }
}

// ---------------- Pass 3: y += qP @ Hcarry; emit y2 (bf16) ----------------
__global__ __launch_bounds__(256) void y_correct(const float* __restrict__ y_loc,
                                                 const float* __restrict__ qP,
                                                 const float* __restrict__ Hc,
                                                 bf16_t* __restrict__ y2b) {
  __shared__ __align__(16) float Hs[D_ * D_ * 2];   // 8 KB
  const int seg = blockIdx.x;
  const int s = seg & (NSEG - 1);
  const int bh = seg >> 6;
  const int h = bh & (H_ - 1), b = bh >> 3;
  const int t = threadIdx.x;
  const float4* src = (const float4*)(Hc + (size_t)seg * (D_ * D_ * 2));
  ((float4*)Hs)[t] = src[t];
  ((float4*)Hs)[t + 256] = src[t + 256];
  __syncthreads();
  const int l = t >> 4;            // 0..15
  const int ep = (t & 15) * 2;     // 2 e per thread
  const int lg = s * LSEG + l;
  const size_t rowc = ((size_t)(b * L_ + lg) * H_ + h) * D_;
  const float* qpr = qP + rowc * 2;
  float4 y0 = *(const float4*)(y_loc + (rowc + ep) * 2);
  float ac_r[2] = {y0.x, y0.z}, ac_i[2] = {y0.y, y0.w};
#pragma unroll 4
  for (int d = 0; d < D_; ++d) {
    float2 p = *(const float2*)(qpr + d * 2);
    float4 hv = *(const float4*)&Hs[(d * D_ + ep) * 2];
    ac_r[0] += p.x * hv.x - p.y * hv.y; ac_i[0] += p.x * hv.y + p.y * hv.x;
    ac_r[1] += p.x * hv.z - p.y * hv.w; ac_i[1] += p.x * hv.w + p.y * hv.z;
  }
  union { bf16_t bv[4]; uint2 q; } pk;
  pk.bv[0] = (bf16_t)ac_r[0]; pk.bv[1] = (bf16_t)ac_i[0];
  pk.bv[2] = (bf16_t)ac_r[1]; pk.bv[3] = (bf16_t)ac_i[1];
  *(uint2*)(y2b + (size_t)(b * L_ + lg) * (H_ * D_ * 2) + (h * D_ + ep) * 2) = pk.q;
}

// ---------------- launcher ------------------------------------------------
extern "C" void kernel_launch(void* const* d_in, const int* in_sizes, int n_in,
                              void* d_out, int out_size, void* d_ws, size_t ws_size,
                              hipStream_t stream) {
  const float* x      = (const float*)d_in[0];
  const float* W_in   = (const float*)d_in[1];
  const float* b_in   = (const float*)d_in[2];
  const float* W_qkva = (const float*)d_in[3];
  const float* b_qkva = (const float*)d_in[4];
  const float* W_y    = (const float*)d_in[5];
  const float* b_y    = (const float*)d_in[6];
  const float* W_out  = (const float*)d_in[7];
  const float* b_out  = (const float*)d_in[8];
  const float* h0re   = (const float*)d_in[9];
  const float* h0im   = (const float*)d_in[10];

  char* w = (char*)d_ws;
  const size_t MB = 1ull << 20;
  bf16_t* Wb_in   = (bf16_t*)(w + 0*MB);    // 2 MB
  bf16_t* Wb_qkva = (bf16_t*)(w + 2*MB);    // 4 MB
  bf16_t* Wb_y    = (bf16_t*)(w + 6*MB);    // 1 MB
  bf16_t* Wb_out  = (bf16_t*)(w + 7*MB);    // 2 MB
  bf16_t* xb      = (bf16_t*)(w + 9*MB);    // 8 MB (dead after GEMM1)
  float*  qP      = (float*) (w + 9*MB);    // 8 MB (overlay xb)
  bf16_t* u       = (bf16_t*)(w + 17*MB);   // 8 MB (dead after GEMM2)
  float*  y_loc   = (float*) (w + 17*MB);   // 8 MB (overlay u)
  float*  qkva    = (float*) (w + 25*MB);   // 32 MB [b,l,h,d,c] (dead after scan)
  float*  Hc      = (float*) (w + 25*MB);   // 16 MB (overlay qkva)
  bf16_t* y2b     = (bf16_t*)(w + 41*MB);   // 4 MB (overlay qkva)
  bf16_t* z       = (bf16_t*)(w + 45*MB);   // 8 MB (overlay qkva)
  float*  Aseg    = (float*) (w + 57*MB);   // 0.5 MB
  float*  Hfin    = (float*) (w + 58*MB);   // 16 MB -> total 74 MB

  cvt_all<<<8704, 256, 0, stream>>>(x, W_in, W_qkva, W_y, W_out,
                                    xb, Wb_in, Wb_qkva, Wb_y, Wb_out);

  // u = silu(x @ W_in^T + b_in)                          512 blocks, BK=128
  gemm_nt64<1,1><<<dim3(32, 16), 256, 0, stream>>>(xb, Wb_in, b_in, u, 4096, 1024, 1024);
  // qkva = gate(u @ W_qkva^T + b_qkva), coalesced f32    512 blocks
  gemm_nt<128,0,0,1><<<dim3(32, 16), 256, 0, stream>>>(u, Wb_qkva, b_qkva, qkva, 4096, 2048, 1024);
  // recurrence
  scan_seg   <<<2048, 256, 0, stream>>>(qkva, y_loc, qP, Aseg, Hfin);
  seg_combine<<<256,  128, 0, stream>>>(h0re, h0im, Aseg, Hfin, Hc);
  y_correct  <<<2048, 256, 0, stream>>>(y_loc, qP, Hc, y2b);
  // z = silu(y2 @ W_y^T + b_y)                           512 blocks, BK=128
  gemm_nt64<1,1><<<dim3(32, 16), 256, 0, stream>>>(y2b, Wb_y, b_y, z, 4096, 1024, 512);
  // out = z @ W_out^T + b_out                            512 blocks, BK=128
  gemm_nt64<0,0><<<dim3(32, 16), 256, 0, stream>>>(z, Wb_out, b_out, (float*)d_out, 4096, 1024, 1024);
}